// Round 2
// baseline (4408.162 us; speedup 1.0000x reference)
//
#include <hip/hip_runtime.h>

typedef __attribute__((ext_vector_type(8))) __bf16 bf16x8;
typedef __attribute__((ext_vector_type(4))) float f32x4;
typedef __attribute__((ext_vector_type(4))) unsigned int u32x4;
typedef __attribute__((ext_vector_type(2))) unsigned int u32x2;

__device__ __forceinline__ unsigned short f2bf(float f) {
  unsigned int u = __float_as_uint(f);
  u += 0x7fffu + ((u >> 16) & 1u);   // RNE
  return (unsigned short)(u >> 16);
}

// ---------------- embedding: x = tok_emb[idx] + pos_emb ----------------
__global__ __launch_bounds__(256) void embed_k(const int* __restrict__ idx,
    const float* __restrict__ tok, const float* __restrict__ pos,
    float* __restrict__ x) {
  int row = blockIdx.x;            // 0..2047 (b*1024+t)
  int t = row & 1023;
  int c = threadIdx.x << 2;
  int id = idx[row];
  f32x4 a = *(const f32x4*)(tok + ((size_t)id << 10) + c);
  f32x4 p = *(const f32x4*)(pos + ((size_t)t << 10) + c);
  a += p;
  *(f32x4*)(x + ((size_t)row << 10) + c) = a;
}

// ---------------- layernorm (f32 in, bf16 out) ----------------
__global__ __launch_bounds__(256) void ln_k(const float* __restrict__ x,
    const float* __restrict__ g, const float* __restrict__ bta,
    unsigned short* __restrict__ out) {
  __shared__ float red[4];
  int row = blockIdx.x, tid = threadIdx.x;
  const float* xr = x + ((size_t)row << 10);
  f32x4 xv = *(const f32x4*)(xr + (tid << 2));
  float s = xv[0] + xv[1] + xv[2] + xv[3];
  #pragma unroll
  for (int off = 32; off; off >>= 1) s += __shfl_xor(s, off);
  if ((tid & 63) == 0) red[tid >> 6] = s;
  __syncthreads();
  float mean = (red[0] + red[1] + red[2] + red[3]) * (1.f / 1024.f);
  __syncthreads();
  f32x4 d = xv - mean;
  float s2 = d[0]*d[0] + d[1]*d[1] + d[2]*d[2] + d[3]*d[3];
  #pragma unroll
  for (int off = 32; off; off >>= 1) s2 += __shfl_xor(s2, off);
  if ((tid & 63) == 0) red[tid >> 6] = s2;
  __syncthreads();
  float var = (red[0] + red[1] + red[2] + red[3]) * (1.f / 1024.f);
  float rs = rsqrtf(var + 1e-5f);
  f32x4 gv = *(const f32x4*)(g + (tid << 2));
  f32x4 bv = *(const f32x4*)(bta + (tid << 2));
  unsigned int p0 = (unsigned int)f2bf(d[0]*rs*gv[0] + bv[0]) |
                    ((unsigned int)f2bf(d[1]*rs*gv[1] + bv[1]) << 16);
  unsigned int p1 = (unsigned int)f2bf(d[2]*rs*gv[2] + bv[2]) |
                    ((unsigned int)f2bf(d[3]*rs*gv[3] + bv[3]) << 16);
  u32x2 o; o[0] = p0; o[1] = p1;
  *(u32x2*)(out + ((size_t)row << 10) + (tid << 2)) = o;
}

// ---------------- generic MFMA GEMM ----------------
// C[M][N] = A(bf16,[M][K]) @ B(f32,[K][N]) (+bias) (+relu) (+resid f32)
// out: bf16 (ob) or f32 (o32). which = blockIdx.x / (N/128) selects B0/B1/B2
// (fused QKV). 128x128 tile, BK=32, 256 thr = 4 waves (2x2), wave = 64x64.
#define TS 40   // LDS row stride (shorts): 80B, 16B-aligned reads, spreads banks
__global__ __launch_bounds__(256) void gemm_k(
    const unsigned short* __restrict__ A,
    const float* __restrict__ B0, const float* __restrict__ B1, const float* __restrict__ B2,
    const float* __restrict__ bias, const float* __restrict__ resid,
    unsigned short* __restrict__ ob0, unsigned short* __restrict__ ob1,
    unsigned short* __restrict__ ob2, float* __restrict__ o32,
    int M, int N, int K, int relu) {
  __shared__ unsigned short As[128 * TS];
  __shared__ unsigned short Bs[128 * TS];   // stored transposed: [n][k]
  int nbp = N >> 7;
  int which = blockIdx.x / nbp;
  int bx = blockIdx.x - which * nbp;
  const float* B = which == 0 ? B0 : (which == 1 ? B1 : B2);
  unsigned short* ob = which == 0 ? ob0 : (which == 1 ? ob1 : ob2);
  int m0 = blockIdx.y << 7, n0 = bx << 7;
  int tid = threadIdx.x, lane = tid & 63, wave = tid >> 6;
  int wr = (wave >> 1) << 6, wc = (wave & 1) << 6;
  int lrow = lane & 15, lk8 = (lane >> 4) << 3;
  int arow = tid >> 1, ac0 = (tid & 1) << 4;
  int bcol = tid & 127, brh = (tid >> 7) << 4;
  f32x4 acc[4][4] = {};
  for (int k0 = 0; k0 < K; k0 += 32) {
    // A stage: 128x32 bf16, 16B x2 per thread
    const u32x4* ag = (const u32x4*)(A + (size_t)(m0 + arow) * K + k0 + ac0);
    u32x4 av0 = ag[0], av1 = ag[1];
    // B stage: 32x128 f32 -> bf16, transposed into Bs[n][k]
    unsigned int bp[8];
    #pragma unroll
    for (int r = 0; r < 8; r++) {
      float f0 = B[(size_t)(k0 + brh + 2*r)     * N + n0 + bcol];
      float f1 = B[(size_t)(k0 + brh + 2*r + 1) * N + n0 + bcol];
      bp[r] = (unsigned int)f2bf(f0) | ((unsigned int)f2bf(f1) << 16);
    }
    *(u32x4*)(As + arow * TS + ac0) = av0;
    *(u32x4*)(As + arow * TS + ac0 + 8) = av1;
    #pragma unroll
    for (int r = 0; r < 4; r++) {
      u32x2 w; w[0] = bp[2*r]; w[1] = bp[2*r + 1];
      *(u32x2*)(Bs + bcol * TS + brh + (r << 2)) = w;
    }
    __syncthreads();
    bf16x8 af[4], bfr[4];
    #pragma unroll
    for (int i = 0; i < 4; i++)
      af[i] = *(const bf16x8*)(As + (wr + (i << 4) + lrow) * TS + lk8);
    #pragma unroll
    for (int i = 0; i < 4; i++)
      bfr[i] = *(const bf16x8*)(Bs + (wc + (i << 4) + lrow) * TS + lk8);
    #pragma unroll
    for (int mi = 0; mi < 4; mi++)
      #pragma unroll
      for (int ni = 0; ni < 4; ni++)
        acc[mi][ni] = __builtin_amdgcn_mfma_f32_16x16x32_bf16(af[mi], bfr[ni], acc[mi][ni], 0, 0, 0);
    __syncthreads();
  }
  int fr = (lane >> 4) << 2;
  #pragma unroll
  for (int mi = 0; mi < 4; mi++) {
    #pragma unroll
    for (int ni = 0; ni < 4; ni++) {
      #pragma unroll
      for (int r = 0; r < 4; r++) {
        int row = m0 + wr + (mi << 4) + fr + r;
        int col = n0 + wc + (ni << 4) + lrow;
        float vv = acc[mi][ni][r];
        if (bias) vv += bias[col];
        if (relu) vv = fmaxf(vv, 0.f);
        size_t off = (size_t)row * N + col;
        if (resid) vv += resid[off];
        if (o32) o32[off] = vv;
        else ob[off] = f2bf(vv);
      }
    }
  }
}

// ---------------- windowed flash attention ----------------
// mask: row t attends s in [511-(t>>1), 511+((t+1)>>1)] (contiguous, width t+1)
// 1 wave per block, 16 q rows, 32-wide s tiles. scale = 1/sqrt(64) = 0.125
__global__ __launch_bounds__(64) void attn_k(
    const unsigned short* __restrict__ q, const unsigned short* __restrict__ k,
    const unsigned short* __restrict__ v, unsigned short* __restrict__ att) {
  __shared__ unsigned short Ks[32 * 72];   // [s][hd], stride 72
  __shared__ unsigned short Vt[64 * 40];   // [hd][s], stride 40
  __shared__ unsigned short Ps[16 * 40];   // [row][s], stride 40
  int t0 = blockIdx.x << 4;
  int h = blockIdx.y, b = blockIdx.z;
  int lane = threadIdx.x;
  int lrow = lane & 15, lk8 = (lane >> 4) << 3;
  int fr = (lane >> 4) << 2;
  size_t qoff = ((size_t)((b << 10) + t0 + lrow) << 10) + (h << 6);
  bf16x8 a0 = *(const bf16x8*)(q + qoff + lk8);
  bf16x8 a1 = *(const bf16x8*)(q + qoff + 32 + lk8);
  float m_[4] = {-1e30f, -1e30f, -1e30f, -1e30f};
  float l_[4] = {0.f, 0.f, 0.f, 0.f};
  f32x4 o_[4] = {};
  int s_lo = (511 - ((t0 + 15) >> 1)) & ~31;
  int s_hi = 511 + ((t0 + 16) >> 1);
  int s_end = (s_hi + 32) & ~31;           // exclusive, 32-aligned, <=1024
  int sr = lane >> 1, c0 = (lane & 1) << 5;
  for (int s0 = s_lo; s0 < s_end; s0 += 32) {
    size_t kvoff = ((size_t)((b << 10) + s0 + sr) << 10) + (h << 6) + c0;
    const u32x4* kg = (const u32x4*)(k + kvoff);
    const u32x4* vg = (const u32x4*)(v + kvoff);
    #pragma unroll
    for (int i = 0; i < 4; i++) {
      u32x4 kv = kg[i];
      *(u32x4*)(Ks + sr * 72 + c0 + (i << 3)) = kv;
      u32x4 vw = vg[i];
      int cb = c0 + (i << 3);
      #pragma unroll
      for (int jj = 0; jj < 4; jj++) {
        unsigned int w = vw[jj];
        Vt[(cb + (jj << 1)) * 40 + sr]     = (unsigned short)(w & 0xffffu);
        Vt[(cb + (jj << 1) + 1) * 40 + sr] = (unsigned short)(w >> 16);
      }
    }
    __syncthreads();
    f32x4 sc0 = {}, sc1 = {};
    {
      bf16x8 kb0 = *(const bf16x8*)(Ks + lrow * 72 + lk8);
      bf16x8 kb1 = *(const bf16x8*)(Ks + lrow * 72 + 32 + lk8);
      sc0 = __builtin_amdgcn_mfma_f32_16x16x32_bf16(a0, kb0, sc0, 0, 0, 0);
      sc0 = __builtin_amdgcn_mfma_f32_16x16x32_bf16(a1, kb1, sc0, 0, 0, 0);
      bf16x8 kb2 = *(const bf16x8*)(Ks + (16 + lrow) * 72 + lk8);
      bf16x8 kb3 = *(const bf16x8*)(Ks + (16 + lrow) * 72 + 32 + lk8);
      sc1 = __builtin_amdgcn_mfma_f32_16x16x32_bf16(a0, kb2, sc1, 0, 0, 0);
      sc1 = __builtin_amdgcn_mfma_f32_16x16x32_bf16(a1, kb3, sc1, 0, 0, 0);
    }
    #pragma unroll
    for (int r = 0; r < 4; r++) {
      int t = t0 + fr + r;
      int lov = 511 - (t >> 1), hiv = 511 + ((t + 1) >> 1);
      int sA = s0 + lrow, sB = sA + 16;
      bool vA = (sA >= lov) && (sA <= hiv);
      bool vB = (sB >= lov) && (sB <= hiv);
      float xA = vA ? sc0[r] * 0.125f : -1e30f;
      float xB = vB ? sc1[r] * 0.125f : -1e30f;
      float tm = fmaxf(xA, xB);
      #pragma unroll
      for (int off = 8; off; off >>= 1) tm = fmaxf(tm, __shfl_xor(tm, off));
      float nm = fmaxf(m_[r], tm);
      float pA = vA ? __expf(xA - nm) : 0.f;
      float pB = vB ? __expf(xB - nm) : 0.f;
      float sca = __expf(m_[r] - nm);
      m_[r] = nm;
      float ps = pA + pB;
      #pragma unroll
      for (int off = 8; off; off >>= 1) ps += __shfl_xor(ps, off);
      l_[r] = l_[r] * sca + ps;
      #pragma unroll
      for (int nb = 0; nb < 4; nb++) o_[nb][r] *= sca;
      Ps[(fr + r) * 40 + lrow]      = f2bf(pA);
      Ps[(fr + r) * 40 + 16 + lrow] = f2bf(pB);
    }
    __syncthreads();
    bf16x8 pa = *(const bf16x8*)(Ps + lrow * 40 + lk8);
    #pragma unroll
    for (int nb = 0; nb < 4; nb++) {
      bf16x8 vb_ = *(const bf16x8*)(Vt + ((nb << 4) + lrow) * 40 + lk8);
      o_[nb] = __builtin_amdgcn_mfma_f32_16x16x32_bf16(pa, vb_, o_[nb], 0, 0, 0);
    }
    __syncthreads();
  }
  #pragma unroll
  for (int nb = 0; nb < 4; nb++)
    #pragma unroll
    for (int r = 0; r < 4; r++) {
      float ov = o_[nb][r] / l_[r];
      att[((size_t)((b << 10) + t0 + fr + r) << 10) + (h << 6) + (nb << 4) + lrow] = f2bf(ov);
    }
}

extern "C" void kernel_launch(void* const* d_in, const int* in_sizes, int n_in,
                              void* d_out, int out_size, void* d_ws, size_t ws_size,
                              hipStream_t stream) {
  (void)in_sizes; (void)n_in; (void)out_size; (void)ws_size;
  const int*   idx  = (const int*)d_in[0];
  const float* tok  = (const float*)d_in[1];
  const float* pos  = (const float*)d_in[2];
  const float* ln1g = (const float*)d_in[3];
  const float* ln1b = (const float*)d_in[4];
  const float* wq   = (const float*)d_in[5];
  const float* wk   = (const float*)d_in[6];
  const float* wv   = (const float*)d_in[7];
  const float* wpj  = (const float*)d_in[8];
  const float* bpj  = (const float*)d_in[9];
  const float* ln2g = (const float*)d_in[10];
  const float* ln2b = (const float*)d_in[11];
  const float* w1   = (const float*)d_in[12];
  const float* b1   = (const float*)d_in[13];
  const float* w2   = (const float*)d_in[14];
  const float* b2   = (const float*)d_in[15];
  const float* lnfg = (const float*)d_in[16];
  const float* lnfb = (const float*)d_in[17];
  const float* wlm  = (const float*)d_in[18];
  const float* blm  = (const float*)d_in[19];
  float* out = (float*)d_out;   // reference output dtype is float32

  char* ws = (char*)d_ws;
  float*          x  = (float*)ws;                                   //  8 MB f32 residual
  unsigned short* hb = (unsigned short*)(ws + (size_t)(8u  << 20));  //  4 MB bf16 LN out
  unsigned short* qb = (unsigned short*)(ws + (size_t)(12u << 20));
  unsigned short* kb = (unsigned short*)(ws + (size_t)(16u << 20));
  unsigned short* vb = (unsigned short*)(ws + (size_t)(20u << 20));
  unsigned short* ab = (unsigned short*)(ws + (size_t)(24u << 20));
  unsigned short* m1 = (unsigned short*)(ws + (size_t)(28u << 20));  // 16 MB bf16

  const int M = 2048, D = 1024;
  embed_k<<<dim3(2048), dim3(256), 0, stream>>>(idx, tok, pos, x);
  for (int l = 0; l < 8; l++) {
    size_t wo = (size_t)l * D * D;
    ln_k<<<2048, 256, 0, stream>>>(x, ln1g + l*D, ln1b + l*D, hb);
    gemm_k<<<dim3(24, 16), 256, 0, stream>>>(hb, wq + wo, wk + wo, wv + wo,
        nullptr, nullptr, qb, kb, vb, nullptr, M, D, D, 0);
    attn_k<<<dim3(64, 16, 2), 64, 0, stream>>>(qb, kb, vb, ab);
    gemm_k<<<dim3(8, 16), 256, 0, stream>>>(ab, wpj + wo, nullptr, nullptr,
        bpj + l*D, x, nullptr, nullptr, nullptr, x, M, D, D, 0);
    ln_k<<<2048, 256, 0, stream>>>(x, ln2g + l*D, ln2b + l*D, hb);
    gemm_k<<<dim3(32, 16), 256, 0, stream>>>(hb, w1 + (size_t)l*D*4*D, nullptr, nullptr,
        b1 + (size_t)l*4*D, nullptr, m1, nullptr, nullptr, nullptr, M, 4*D, D, 1);
    gemm_k<<<dim3(8, 16), 256, 0, stream>>>(m1, w2 + (size_t)l*4*D*D, nullptr, nullptr,
        b2 + l*D, x, nullptr, nullptr, nullptr, x, M, D, 4*D, 0);
  }
  ln_k<<<2048, 256, 0, stream>>>(x, lnfg, lnfb, hb);
  gemm_k<<<dim3(500, 16), 256, 0, stream>>>(hb, wlm, nullptr, nullptr,
      blm, nullptr, nullptr, nullptr, nullptr, out, M, 64000, D, 0);
}

// Round 3
// 3019.466 us; speedup vs baseline: 1.4599x; 1.4599x over previous
//
#include <hip/hip_runtime.h>

typedef __attribute__((ext_vector_type(8))) __bf16 bf16x8;
typedef __attribute__((ext_vector_type(4))) float f32x4;
typedef __attribute__((ext_vector_type(4))) unsigned int u32x4;
typedef __attribute__((ext_vector_type(2))) unsigned int u32x2;

__device__ __forceinline__ unsigned short f2bf(float f) {
  unsigned int u = __float_as_uint(f);
  u += 0x7fffu + ((u >> 16) & 1u);   // RNE
  return (unsigned short)(u >> 16);
}

__device__ __forceinline__ void gload16(const void* g, void* l) {
  __builtin_amdgcn_global_load_lds(
      (const __attribute__((address_space(1))) unsigned int*)g,
      (__attribute__((address_space(3))) unsigned int*)l, 16, 0, 0);
}

// ---------------- embedding ----------------
__global__ __launch_bounds__(256) void embed_k(const int* __restrict__ idx,
    const float* __restrict__ tok, const float* __restrict__ pos,
    float* __restrict__ x) {
  int row = blockIdx.x;
  int t = row & 1023;
  int c = threadIdx.x << 2;
  int id = idx[row];
  f32x4 a = *(const f32x4*)(tok + ((size_t)id << 10) + c);
  f32x4 p = *(const f32x4*)(pos + ((size_t)t << 10) + c);
  a += p;
  *(f32x4*)(x + ((size_t)row << 10) + c) = a;
}

// ---------------- layernorm (f32 in, bf16 out) ----------------
__global__ __launch_bounds__(256) void ln_k(const float* __restrict__ x,
    const float* __restrict__ g, const float* __restrict__ bta,
    unsigned short* __restrict__ out) {
  __shared__ float red[4];
  int row = blockIdx.x, tid = threadIdx.x;
  const float* xr = x + ((size_t)row << 10);
  f32x4 xv = *(const f32x4*)(xr + (tid << 2));
  float s = xv[0] + xv[1] + xv[2] + xv[3];
  #pragma unroll
  for (int off = 32; off; off >>= 1) s += __shfl_xor(s, off);
  if ((tid & 63) == 0) red[tid >> 6] = s;
  __syncthreads();
  float mean = (red[0] + red[1] + red[2] + red[3]) * (1.f / 1024.f);
  __syncthreads();
  f32x4 d = xv - mean;
  float s2 = d[0]*d[0] + d[1]*d[1] + d[2]*d[2] + d[3]*d[3];
  #pragma unroll
  for (int off = 32; off; off >>= 1) s2 += __shfl_xor(s2, off);
  if ((tid & 63) == 0) red[tid >> 6] = s2;
  __syncthreads();
  float var = (red[0] + red[1] + red[2] + red[3]) * (1.f / 1024.f);
  float rs = rsqrtf(var + 1e-5f);
  f32x4 gv = *(const f32x4*)(g + (tid << 2));
  f32x4 bv = *(const f32x4*)(bta + (tid << 2));
  unsigned int p0 = (unsigned int)f2bf(d[0]*rs*gv[0] + bv[0]) |
                    ((unsigned int)f2bf(d[1]*rs*gv[1] + bv[1]) << 16);
  unsigned int p1 = (unsigned int)f2bf(d[2]*rs*gv[2] + bv[2]) |
                    ((unsigned int)f2bf(d[3]*rs*gv[3] + bv[3]) << 16);
  u32x2 o; o[0] = p0; o[1] = p1;
  *(u32x2*)(out + ((size_t)row << 10) + (tid << 2)) = o;
}

// ---------------- weight transpose: f32 [R][C] -> bf16 [C][R] ----------------
__global__ __launch_bounds__(256) void transp_k(const float* __restrict__ in,
    unsigned short* __restrict__ out, int R, int C) {
  __shared__ unsigned short tile[64 * 65];
  size_t lay = (size_t)blockIdx.z * R * C;
  int c0 = blockIdx.x << 6, r0 = blockIdx.y << 6;
  int t = threadIdx.x;
  #pragma unroll
  for (int i = 0; i < 4; i++) {
    int e = (i << 10) + (t << 2);
    int r = e >> 6, c = e & 63;
    f32x4 v = *(const f32x4*)(in + lay + (size_t)(r0 + r) * C + c0 + c);
    tile[r * 65 + c]     = f2bf(v[0]);
    tile[r * 65 + c + 1] = f2bf(v[1]);
    tile[r * 65 + c + 2] = f2bf(v[2]);
    tile[r * 65 + c + 3] = f2bf(v[3]);
  }
  __syncthreads();
  #pragma unroll
  for (int i = 0; i < 4; i++) {
    int e = (i << 10) + (t << 2);
    int cc = e >> 6, rr = e & 63;
    unsigned int a0 = tile[(rr + 0) * 65 + cc];
    unsigned int a1 = tile[(rr + 1) * 65 + cc];
    unsigned int a2 = tile[(rr + 2) * 65 + cc];
    unsigned int a3 = tile[(rr + 3) * 65 + cc];
    u32x2 pk; pk[0] = a0 | (a1 << 16); pk[1] = a2 | (a3 << 16);
    *(u32x2*)(out + lay + (size_t)(c0 + cc) * R + r0 + rr) = pk;
  }
}

// ---------------- m97-structure GEMM: A bf16 [M][K] @ Bt bf16 [N][K] ----------------
// 128x128 tile, BK=64, 4 waves (2x2), global_load_lds staging, 2-barrier loop.
// which = blockIdx.x/(N/128): 0->ob0/o32, 1->ob1, 2->vtout ([b][h][d][t] transposed V)
__global__ __launch_bounds__(256) void gemm_bt(
    const unsigned short* __restrict__ A,
    const unsigned short* __restrict__ Bt0, const unsigned short* __restrict__ Bt1,
    const unsigned short* __restrict__ Bt2,
    const float* __restrict__ bias, const float* resid,
    unsigned short* __restrict__ ob0, unsigned short* __restrict__ ob1,
    unsigned short* __restrict__ vtout, float* o32,
    int M, int N, int K, int relu) {
  __shared__ unsigned short As[128 * 64];
  __shared__ unsigned short Bs[128 * 64];
  int nbp = N >> 7;
  int which = blockIdx.x / nbp;
  int bx = blockIdx.x - which * nbp;
  const unsigned short* Bt = which == 0 ? Bt0 : (which == 1 ? Bt1 : Bt2);
  int m0 = blockIdx.y << 7, n0 = bx << 7;
  int tid = threadIdx.x, lane = tid & 63, wave = tid >> 6;
  int wr = (wave >> 1) << 6, wc = (wave & 1) << 6;
  int lrow = lane & 15, lk8 = (lane >> 4) << 3;
  int wbase = wave << 12;                  // byte base of this wave's 4KB staging chunk
  f32x4 acc[4][4] = {};
  const unsigned short* Ag = A + (size_t)m0 * K;
  const unsigned short* Bg = Bt + (size_t)n0 * K;
  for (int k0 = 0; k0 < K; k0 += 64) {
    #pragma unroll
    for (int i = 0; i < 4; i++) {
      int o = wbase + (i << 10) + (lane << 4);   // byte offset in 16KB tile
      int r = o >> 7, c = (o & 127) >> 1;        // row, short col
      gload16(Ag + (size_t)r * K + k0 + c, (char*)As + wbase + (i << 10));
      gload16(Bg + (size_t)r * K + k0 + c, (char*)Bs + wbase + (i << 10));
    }
    __syncthreads();
    #pragma unroll
    for (int ks = 0; ks < 2; ks++) {
      bf16x8 af[4], bfv[4];
      #pragma unroll
      for (int i = 0; i < 4; i++)
        af[i] = *(const bf16x8*)(As + ((wr + (i << 4) + lrow) << 6) + (ks << 5) + lk8);
      #pragma unroll
      for (int i = 0; i < 4; i++)
        bfv[i] = *(const bf16x8*)(Bs + ((wc + (i << 4) + lrow) << 6) + (ks << 5) + lk8);
      #pragma unroll
      for (int mi = 0; mi < 4; mi++)
        #pragma unroll
        for (int ni = 0; ni < 4; ni++)
          acc[mi][ni] = __builtin_amdgcn_mfma_f32_16x16x32_bf16(af[mi], bfv[ni], acc[mi][ni], 0, 0, 0);
    }
    __syncthreads();
  }
  int fr = (lane >> 4) << 2;
  #pragma unroll
  for (int mi = 0; mi < 4; mi++) {
    #pragma unroll
    for (int ni = 0; ni < 4; ni++) {
      int row = m0 + wr + (mi << 4) + fr;
      int col = n0 + wc + (ni << 4) + lrow;
      f32x4 av = acc[mi][ni];
      if (bias) {
        float bb = bias[col];
        av[0] += bb; av[1] += bb; av[2] += bb; av[3] += bb;
      }
      if (relu) {
        av[0] = fmaxf(av[0], 0.f); av[1] = fmaxf(av[1], 0.f);
        av[2] = fmaxf(av[2], 0.f); av[3] = fmaxf(av[3], 0.f);
      }
      if (which == 2) {
        // V transposed out: vt[((b*16+h)*64+d)*1024 + t]
        u32x2 pk;
        pk[0] = (unsigned int)f2bf(av[0]) | ((unsigned int)f2bf(av[1]) << 16);
        pk[1] = (unsigned int)f2bf(av[2]) | ((unsigned int)f2bf(av[3]) << 16);
        *(u32x2*)(vtout + (((size_t)(row >> 10) * 16 + (col >> 6)) * 64 + (col & 63)) * 1024
                  + (row & 1023)) = pk;
      } else if (o32) {
        #pragma unroll
        for (int r = 0; r < 4; r++) {
          size_t off = (size_t)(row + r) * N + col;
          float vvv = av[r];
          if (resid) vvv += resid[off];
          o32[off] = vvv;
        }
      } else {
        unsigned short* ob = which == 0 ? ob0 : ob1;
        #pragma unroll
        for (int r = 0; r < 4; r++)
          ob[(size_t)(row + r) * N + col] = f2bf(av[r]);
      }
    }
  }
}

// ---------------- windowed flash attention, 4 waves/block, V from vt ----------------
__global__ __launch_bounds__(256) void attn4_k(
    const unsigned short* __restrict__ q, const unsigned short* __restrict__ k,
    const unsigned short* __restrict__ vt, unsigned short* __restrict__ att) {
  __shared__ unsigned short Ks[32 * 72];     // [s][hd]
  __shared__ unsigned short Vt[64 * 40];     // [hd][s]
  __shared__ unsigned short Ps[4][16 * 40];  // per-wave [row][s]
  int t0 = blockIdx.x << 6;
  int h = blockIdx.y, b = blockIdx.z;
  int tid = threadIdx.x, lane = tid & 63, w = tid >> 6;
  int lrow = lane & 15, lk8 = (lane >> 4) << 3, fr = (lane >> 4) << 2;
  int qrow = t0 + (w << 4) + lrow;
  size_t qoff = ((size_t)((b << 10) + qrow) << 10) + (h << 6);
  bf16x8 a0 = *(const bf16x8*)(q + qoff + lk8);
  bf16x8 a1 = *(const bf16x8*)(q + qoff + 32 + lk8);
  float m_[4] = {-1e30f, -1e30f, -1e30f, -1e30f};
  float l_[4] = {0.f, 0.f, 0.f, 0.f};
  f32x4 o_[4] = {};
  int s_lo = (511 - ((t0 + 63) >> 1)) & ~31;
  int s_hi = 511 + ((t0 + 64) >> 1);
  int s_end = (s_hi + 32) & ~31;
  int krow = tid >> 3, ks0 = (tid & 7) << 3;       // K stage: row, short col
  int vd = tid >> 2, vs0 = (tid & 3) << 3;         // V stage: d row, s col
  size_t vbase = ((size_t)((b << 4) + h) << 16) + ((size_t)vd << 10);
  unsigned short* Psw = &Ps[w][0];
  for (int s0 = s_lo; s0 < s_end; s0 += 32) {
    u32x4 kv = *(const u32x4*)(k + (((size_t)((b << 10) + s0 + krow)) << 10) + (h << 6) + ks0);
    u32x4 vv = *(const u32x4*)(vt + vbase + s0 + vs0);
    *(u32x4*)(Ks + krow * 72 + ks0) = kv;
    *(u32x4*)(Vt + vd * 40 + vs0) = vv;
    __syncthreads();
    f32x4 sc0 = {}, sc1 = {};
    {
      bf16x8 kb0 = *(const bf16x8*)(Ks + lrow * 72 + lk8);
      bf16x8 kb1 = *(const bf16x8*)(Ks + lrow * 72 + 32 + lk8);
      sc0 = __builtin_amdgcn_mfma_f32_16x16x32_bf16(a0, kb0, sc0, 0, 0, 0);
      sc0 = __builtin_amdgcn_mfma_f32_16x16x32_bf16(a1, kb1, sc0, 0, 0, 0);
      bf16x8 kb2 = *(const bf16x8*)(Ks + (16 + lrow) * 72 + lk8);
      bf16x8 kb3 = *(const bf16x8*)(Ks + (16 + lrow) * 72 + 32 + lk8);
      sc1 = __builtin_amdgcn_mfma_f32_16x16x32_bf16(a0, kb2, sc1, 0, 0, 0);
      sc1 = __builtin_amdgcn_mfma_f32_16x16x32_bf16(a1, kb3, sc1, 0, 0, 0);
    }
    #pragma unroll
    for (int r = 0; r < 4; r++) {
      int t = t0 + (w << 4) + fr + r;
      int lov = 511 - (t >> 1), hiv = 511 + ((t + 1) >> 1);
      int sA = s0 + lrow, sB = sA + 16;
      bool vA = (sA >= lov) && (sA <= hiv);
      bool vB = (sB >= lov) && (sB <= hiv);
      float xA = vA ? sc0[r] * 0.125f : -1e30f;
      float xB = vB ? sc1[r] * 0.125f : -1e30f;
      float tm = fmaxf(xA, xB);
      #pragma unroll
      for (int off = 8; off; off >>= 1) tm = fmaxf(tm, __shfl_xor(tm, off));
      float nm = fmaxf(m_[r], tm);
      float pA = vA ? __expf(xA - nm) : 0.f;
      float pB = vB ? __expf(xB - nm) : 0.f;
      float sca = __expf(m_[r] - nm);
      m_[r] = nm;
      float ps = pA + pB;
      #pragma unroll
      for (int off = 8; off; off >>= 1) ps += __shfl_xor(ps, off);
      l_[r] = l_[r] * sca + ps;
      #pragma unroll
      for (int nb = 0; nb < 4; nb++) o_[nb][r] *= sca;
      Psw[(fr + r) * 40 + lrow]      = f2bf(pA);
      Psw[(fr + r) * 40 + 16 + lrow] = f2bf(pB);
    }
    bf16x8 pa = *(const bf16x8*)(Psw + lrow * 40 + lk8);
    #pragma unroll
    for (int nb = 0; nb < 4; nb++) {
      bf16x8 vb_ = *(const bf16x8*)(Vt + ((nb << 4) + lrow) * 40 + lk8);
      o_[nb] = __builtin_amdgcn_mfma_f32_16x16x32_bf16(pa, vb_, o_[nb], 0, 0, 0);
    }
    __syncthreads();
  }
  #pragma unroll
  for (int nb = 0; nb < 4; nb++)
    #pragma unroll
    for (int r = 0; r < 4; r++) {
      float ov = o_[nb][r] / l_[r];
      att[((size_t)((b << 10) + t0 + (w << 4) + fr + r) << 10) + (h << 6) + (nb << 4) + lrow]
          = f2bf(ov);
    }
}

// ================= fallback (round-2 proven) kernels =================
#define TS 40
__global__ __launch_bounds__(256) void gemm_k(
    const unsigned short* __restrict__ A,
    const float* __restrict__ B0, const float* __restrict__ B1, const float* __restrict__ B2,
    const float* __restrict__ bias, const float* resid,
    unsigned short* __restrict__ ob0, unsigned short* __restrict__ ob1,
    unsigned short* __restrict__ ob2, float* o32,
    int M, int N, int K, int relu) {
  __shared__ unsigned short As[128 * TS];
  __shared__ unsigned short Bs[128 * TS];
  int nbp = N >> 7;
  int which = blockIdx.x / nbp;
  int bx = blockIdx.x - which * nbp;
  const float* B = which == 0 ? B0 : (which == 1 ? B1 : B2);
  unsigned short* ob = which == 0 ? ob0 : (which == 1 ? ob1 : ob2);
  int m0 = blockIdx.y << 7, n0 = bx << 7;
  int tid = threadIdx.x, lane = tid & 63, wave = tid >> 6;
  int wr = (wave >> 1) << 6, wc = (wave & 1) << 6;
  int lrow = lane & 15, lk8 = (lane >> 4) << 3;
  int arow = tid >> 1, ac0 = (tid & 1) << 4;
  int bcol = tid & 127, brh = (tid >> 7) << 4;
  f32x4 acc[4][4] = {};
  for (int k0 = 0; k0 < K; k0 += 32) {
    const u32x4* ag = (const u32x4*)(A + (size_t)(m0 + arow) * K + k0 + ac0);
    u32x4 av0 = ag[0], av1 = ag[1];
    unsigned int bp[8];
    #pragma unroll
    for (int r = 0; r < 8; r++) {
      float f0 = B[(size_t)(k0 + brh + 2*r)     * N + n0 + bcol];
      float f1 = B[(size_t)(k0 + brh + 2*r + 1) * N + n0 + bcol];
      bp[r] = (unsigned int)f2bf(f0) | ((unsigned int)f2bf(f1) << 16);
    }
    *(u32x4*)(As + arow * TS + ac0) = av0;
    *(u32x4*)(As + arow * TS + ac0 + 8) = av1;
    #pragma unroll
    for (int r = 0; r < 4; r++) {
      u32x2 wv; wv[0] = bp[2*r]; wv[1] = bp[2*r + 1];
      *(u32x2*)(Bs + bcol * TS + brh + (r << 2)) = wv;
    }
    __syncthreads();
    bf16x8 af[4], bfr[4];
    #pragma unroll
    for (int i = 0; i < 4; i++)
      af[i] = *(const bf16x8*)(As + (wr + (i << 4) + lrow) * TS + lk8);
    #pragma unroll
    for (int i = 0; i < 4; i++)
      bfr[i] = *(const bf16x8*)(Bs + (wc + (i << 4) + lrow) * TS + lk8);
    #pragma unroll
    for (int mi = 0; mi < 4; mi++)
      #pragma unroll
      for (int ni = 0; ni < 4; ni++)
        acc[mi][ni] = __builtin_amdgcn_mfma_f32_16x16x32_bf16(af[mi], bfr[ni], acc[mi][ni], 0, 0, 0);
    __syncthreads();
  }
  int fr = (lane >> 4) << 2;
  #pragma unroll
  for (int mi = 0; mi < 4; mi++) {
    #pragma unroll
    for (int ni = 0; ni < 4; ni++) {
      #pragma unroll
      for (int r = 0; r < 4; r++) {
        int row = m0 + wr + (mi << 4) + fr + r;
        int col = n0 + wc + (ni << 4) + lrow;
        float vv = acc[mi][ni][r];
        if (bias) vv += bias[col];
        if (relu) vv = fmaxf(vv, 0.f);
        size_t off = (size_t)row * N + col;
        if (resid) vv += resid[off];
        if (o32) o32[off] = vv;
        else ob[off] = f2bf(vv);
      }
    }
  }
}

__global__ __launch_bounds__(64) void attn_k(
    const unsigned short* __restrict__ q, const unsigned short* __restrict__ k,
    const unsigned short* __restrict__ v, unsigned short* __restrict__ att) {
  __shared__ unsigned short Ks[32 * 72];
  __shared__ unsigned short Vt[64 * 40];
  __shared__ unsigned short Ps[16 * 40];
  int t0 = blockIdx.x << 4;
  int h = blockIdx.y, b = blockIdx.z;
  int lane = threadIdx.x;
  int lrow = lane & 15, lk8 = (lane >> 4) << 3;
  int fr = (lane >> 4) << 2;
  size_t qoff = ((size_t)((b << 10) + t0 + lrow) << 10) + (h << 6);
  bf16x8 a0 = *(const bf16x8*)(q + qoff + lk8);
  bf16x8 a1 = *(const bf16x8*)(q + qoff + 32 + lk8);
  float m_[4] = {-1e30f, -1e30f, -1e30f, -1e30f};
  float l_[4] = {0.f, 0.f, 0.f, 0.f};
  f32x4 o_[4] = {};
  int s_lo = (511 - ((t0 + 15) >> 1)) & ~31;
  int s_hi = 511 + ((t0 + 16) >> 1);
  int s_end = (s_hi + 32) & ~31;
  int sr = lane >> 1, c0 = (lane & 1) << 5;
  for (int s0 = s_lo; s0 < s_end; s0 += 32) {
    size_t kvoff = ((size_t)((b << 10) + s0 + sr) << 10) + (h << 6) + c0;
    const u32x4* kg = (const u32x4*)(k + kvoff);
    const u32x4* vg = (const u32x4*)(v + kvoff);
    #pragma unroll
    for (int i = 0; i < 4; i++) {
      u32x4 kv = kg[i];
      *(u32x4*)(Ks + sr * 72 + c0 + (i << 3)) = kv;
      u32x4 vw = vg[i];
      int cb = c0 + (i << 3);
      #pragma unroll
      for (int jj = 0; jj < 4; jj++) {
        unsigned int wv = vw[jj];
        Vt[(cb + (jj << 1)) * 40 + sr]     = (unsigned short)(wv & 0xffffu);
        Vt[(cb + (jj << 1) + 1) * 40 + sr] = (unsigned short)(wv >> 16);
      }
    }
    __syncthreads();
    f32x4 sc0 = {}, sc1 = {};
    {
      bf16x8 kb0 = *(const bf16x8*)(Ks + lrow * 72 + lk8);
      bf16x8 kb1 = *(const bf16x8*)(Ks + lrow * 72 + 32 + lk8);
      sc0 = __builtin_amdgcn_mfma_f32_16x16x32_bf16(a0, kb0, sc0, 0, 0, 0);
      sc0 = __builtin_amdgcn_mfma_f32_16x16x32_bf16(a1, kb1, sc0, 0, 0, 0);
      bf16x8 kb2 = *(const bf16x8*)(Ks + (16 + lrow) * 72 + lk8);
      bf16x8 kb3 = *(const bf16x8*)(Ks + (16 + lrow) * 72 + 32 + lk8);
      sc1 = __builtin_amdgcn_mfma_f32_16x16x32_bf16(a0, kb2, sc1, 0, 0, 0);
      sc1 = __builtin_amdgcn_mfma_f32_16x16x32_bf16(a1, kb3, sc1, 0, 0, 0);
    }
    #pragma unroll
    for (int r = 0; r < 4; r++) {
      int t = t0 + fr + r;
      int lov = 511 - (t >> 1), hiv = 511 + ((t + 1) >> 1);
      int sA = s0 + lrow, sB = sA + 16;
      bool vA = (sA >= lov) && (sA <= hiv);
      bool vB = (sB >= lov) && (sB <= hiv);
      float xA = vA ? sc0[r] * 0.125f : -1e30f;
      float xB = vB ? sc1[r] * 0.125f : -1e30f;
      float tm = fmaxf(xA, xB);
      #pragma unroll
      for (int off = 8; off; off >>= 1) tm = fmaxf(tm, __shfl_xor(tm, off));
      float nm = fmaxf(m_[r], tm);
      float pA = vA ? __expf(xA - nm) : 0.f;
      float pB = vB ? __expf(xB - nm) : 0.f;
      float sca = __expf(m_[r] - nm);
      m_[r] = nm;
      float ps = pA + pB;
      #pragma unroll
      for (int off = 8; off; off >>= 1) ps += __shfl_xor(ps, off);
      l_[r] = l_[r] * sca + ps;
      #pragma unroll
      for (int nb = 0; nb < 4; nb++) o_[nb][r] *= sca;
      Ps[(fr + r) * 40 + lrow]      = f2bf(pA);
      Ps[(fr + r) * 40 + 16 + lrow] = f2bf(pB);
    }
    __syncthreads();
    bf16x8 pa = *(const bf16x8*)(Ps + lrow * 40 + lk8);
    #pragma unroll
    for (int nb = 0; nb < 4; nb++) {
      bf16x8 vb_ = *(const bf16x8*)(Vt + ((nb << 4) + lrow) * 40 + lk8);
      o_[nb] = __builtin_amdgcn_mfma_f32_16x16x32_bf16(pa, vb_, o_[nb], 0, 0, 0);
    }
    __syncthreads();
  }
  #pragma unroll
  for (int nb = 0; nb < 4; nb++)
    #pragma unroll
    for (int r = 0; r < 4; r++) {
      float ov = o_[nb][r] / l_[r];
      att[((size_t)((b << 10) + t0 + fr + r) << 10) + (h << 6) + (nb << 4) + lrow] = f2bf(ov);
    }
}

extern "C" void kernel_launch(void* const* d_in, const int* in_sizes, int n_in,
                              void* d_out, int out_size, void* d_ws, size_t ws_size,
                              hipStream_t stream) {
  (void)in_sizes; (void)n_in; (void)out_size;
  const int*   idx  = (const int*)d_in[0];
  const float* tok  = (const float*)d_in[1];
  const float* pos  = (const float*)d_in[2];
  const float* ln1g = (const float*)d_in[3];
  const float* ln1b = (const float*)d_in[4];
  const float* wq   = (const float*)d_in[5];
  const float* wk   = (const float*)d_in[6];
  const float* wv   = (const float*)d_in[7];
  const float* wpj  = (const float*)d_in[8];
  const float* bpj  = (const float*)d_in[9];
  const float* ln2g = (const float*)d_in[10];
  const float* ln2b = (const float*)d_in[11];
  const float* w1   = (const float*)d_in[12];
  const float* b1   = (const float*)d_in[13];
  const float* w2   = (const float*)d_in[14];
  const float* b2   = (const float*)d_in[15];
  const float* lnfg = (const float*)d_in[16];
  const float* lnfb = (const float*)d_in[17];
  const float* wlm  = (const float*)d_in[18];
  const float* blm  = (const float*)d_in[19];
  float* out = (float*)d_out;

  char* ws = (char*)d_ws;
  const size_t MB = 1u << 20;
  float*          x    = (float*)ws;
  unsigned short* hb   = (unsigned short*)(ws + 8 * MB);
  unsigned short* qb   = (unsigned short*)(ws + 12 * MB);
  unsigned short* kb   = (unsigned short*)(ws + 16 * MB);
  unsigned short* vbuf = (unsigned short*)(ws + 20 * MB);
  unsigned short* ab   = (unsigned short*)(ws + 24 * MB);
  unsigned short* m1   = (unsigned short*)(ws + 28 * MB);
  const int M = 2048, D = 1024;
  bool big = ws_size >= 362 * MB;

  embed_k<<<dim3(2048), dim3(256), 0, stream>>>(idx, tok, pos, x);

  if (big) {
    unsigned short* wqT  = (unsigned short*)(ws + 44 * MB);
    unsigned short* wkT  = (unsigned short*)(ws + 60 * MB);
    unsigned short* wvT  = (unsigned short*)(ws + 76 * MB);
    unsigned short* wpT  = (unsigned short*)(ws + 92 * MB);
    unsigned short* w1T  = (unsigned short*)(ws + 108 * MB);
    unsigned short* w2T  = (unsigned short*)(ws + 172 * MB);
    unsigned short* wlmT = (unsigned short*)(ws + 236 * MB);
    transp_k<<<dim3(16, 16, 8), 256, 0, stream>>>(wq,   wqT,  1024, 1024);
    transp_k<<<dim3(16, 16, 8), 256, 0, stream>>>(wk,   wkT,  1024, 1024);
    transp_k<<<dim3(16, 16, 8), 256, 0, stream>>>(wv,   wvT,  1024, 1024);
    transp_k<<<dim3(16, 16, 8), 256, 0, stream>>>(wpj,  wpT,  1024, 1024);
    transp_k<<<dim3(64, 16, 8), 256, 0, stream>>>(w1,   w1T,  1024, 4096);
    transp_k<<<dim3(16, 64, 8), 256, 0, stream>>>(w2,   w2T,  4096, 1024);
    transp_k<<<dim3(1000, 16, 1), 256, 0, stream>>>(wlm, wlmT, 1024, 64000);
    for (int l = 0; l < 8; l++) {
      size_t wo = (size_t)l << 20;
      ln_k<<<2048, 256, 0, stream>>>(x, ln1g + l*D, ln1b + l*D, hb);
      gemm_bt<<<dim3(24, 16), 256, 0, stream>>>(hb, wqT + wo, wkT + wo, wvT + wo,
          nullptr, nullptr, qb, kb, vbuf, nullptr, M, D, D, 0);
      attn4_k<<<dim3(16, 16, 2), 256, 0, stream>>>(qb, kb, vbuf, ab);
      gemm_bt<<<dim3(8, 16), 256, 0, stream>>>(ab, wpT + wo, nullptr, nullptr,
          bpj + l*D, x, nullptr, nullptr, nullptr, x, M, D, D, 0);
      ln_k<<<2048, 256, 0, stream>>>(x, ln2g + l*D, ln2b + l*D, hb);
      gemm_bt<<<dim3(32, 16), 256, 0, stream>>>(hb, w1T + ((size_t)l << 22), nullptr, nullptr,
          b1 + (size_t)l*4*D, nullptr, m1, nullptr, nullptr, nullptr, M, 4*D, D, 1);
      gemm_bt<<<dim3(8, 16), 256, 0, stream>>>(m1, w2T + ((size_t)l << 22), nullptr, nullptr,
          b2 + l*D, x, nullptr, nullptr, nullptr, x, M, D, 4*D, 0);
    }
    ln_k<<<2048, 256, 0, stream>>>(x, lnfg, lnfb, hb);
    gemm_bt<<<dim3(500, 16), 256, 0, stream>>>(hb, wlmT, nullptr, nullptr,
        blm, nullptr, nullptr, nullptr, nullptr, out, M, 64000, D, 0);
  } else {
    for (int l = 0; l < 8; l++) {
      size_t wo = (size_t)l * D * D;
      ln_k<<<2048, 256, 0, stream>>>(x, ln1g + l*D, ln1b + l*D, hb);
      gemm_k<<<dim3(24, 16), 256, 0, stream>>>(hb, wq + wo, wk + wo, wv + wo,
          nullptr, nullptr, qb, kb, vbuf, nullptr, M, D, D, 0);
      attn_k<<<dim3(64, 16, 2), 64, 0, stream>>>(qb, kb, vbuf, ab);
      gemm_k<<<dim3(8, 16), 256, 0, stream>>>(ab, wpj + wo, nullptr, nullptr,
          bpj + l*D, x, nullptr, nullptr, nullptr, x, M, D, D, 0);
      ln_k<<<2048, 256, 0, stream>>>(x, ln2g + l*D, ln2b + l*D, hb);
      gemm_k<<<dim3(32, 16), 256, 0, stream>>>(hb, w1 + (size_t)l*D*4*D, nullptr, nullptr,
          b1 + (size_t)l*4*D, nullptr, m1, nullptr, nullptr, nullptr, M, 4*D, D, 1);
      gemm_k<<<dim3(8, 16), 256, 0, stream>>>(m1, w2 + (size_t)l*4*D*D, nullptr, nullptr,
          b2 + l*D, x, nullptr, nullptr, nullptr, x, M, D, 4*D, 0);
    }
    ln_k<<<2048, 256, 0, stream>>>(x, lnfg, lnfb, hb);
    gemm_k<<<dim3(500, 16), 256, 0, stream>>>(hb, wlm, nullptr, nullptr,
        blm, nullptr, nullptr, nullptr, nullptr, out, M, 64000, D, 0);
  }
}

// Round 4
// 2939.490 us; speedup vs baseline: 1.4996x; 1.0272x over previous
//
#include <hip/hip_runtime.h>

typedef __attribute__((ext_vector_type(8))) __bf16 bf16x8;
typedef __attribute__((ext_vector_type(4))) float f32x4;
typedef __attribute__((ext_vector_type(4))) unsigned int u32x4;
typedef __attribute__((ext_vector_type(2))) unsigned int u32x2;

__device__ __forceinline__ unsigned short f2bf(float f) {
  unsigned int u = __float_as_uint(f);
  u += 0x7fffu + ((u >> 16) & 1u);   // RNE
  return (unsigned short)(u >> 16);
}

__device__ __forceinline__ void gload16(const void* g, void* l) {
  __builtin_amdgcn_global_load_lds(
      (const __attribute__((address_space(1))) unsigned int*)g,
      (__attribute__((address_space(3))) unsigned int*)l, 16, 0, 0);
}

// ---------------- embedding ----------------
__global__ __launch_bounds__(256) void embed_k(const int* __restrict__ idx,
    const float* __restrict__ tok, const float* __restrict__ pos,
    float* __restrict__ x) {
  int row = blockIdx.x;
  int t = row & 1023;
  int c = threadIdx.x << 2;
  int id = idx[row];
  f32x4 a = *(const f32x4*)(tok + ((size_t)id << 10) + c);
  f32x4 p = *(const f32x4*)(pos + ((size_t)t << 10) + c);
  a += p;
  *(f32x4*)(x + ((size_t)row << 10) + c) = a;
}

// ---------------- layernorm (f32 in, bf16 out) ----------------
__global__ __launch_bounds__(256) void ln_k(const float* __restrict__ x,
    const float* __restrict__ g, const float* __restrict__ bta,
    unsigned short* __restrict__ out) {
  __shared__ float red[4];
  int row = blockIdx.x, tid = threadIdx.x;
  const float* xr = x + ((size_t)row << 10);
  f32x4 xv = *(const f32x4*)(xr + (tid << 2));
  float s = xv[0] + xv[1] + xv[2] + xv[3];
  #pragma unroll
  for (int off = 32; off; off >>= 1) s += __shfl_xor(s, off);
  if ((tid & 63) == 0) red[tid >> 6] = s;
  __syncthreads();
  float mean = (red[0] + red[1] + red[2] + red[3]) * (1.f / 1024.f);
  __syncthreads();
  f32x4 d = xv - mean;
  float s2 = d[0]*d[0] + d[1]*d[1] + d[2]*d[2] + d[3]*d[3];
  #pragma unroll
  for (int off = 32; off; off >>= 1) s2 += __shfl_xor(s2, off);
  if ((tid & 63) == 0) red[tid >> 6] = s2;
  __syncthreads();
  float var = (red[0] + red[1] + red[2] + red[3]) * (1.f / 1024.f);
  float rs = rsqrtf(var + 1e-5f);
  f32x4 gv = *(const f32x4*)(g + (tid << 2));
  f32x4 bv = *(const f32x4*)(bta + (tid << 2));
  unsigned int p0 = (unsigned int)f2bf(d[0]*rs*gv[0] + bv[0]) |
                    ((unsigned int)f2bf(d[1]*rs*gv[1] + bv[1]) << 16);
  unsigned int p1 = (unsigned int)f2bf(d[2]*rs*gv[2] + bv[2]) |
                    ((unsigned int)f2bf(d[3]*rs*gv[3] + bv[3]) << 16);
  u32x2 o; o[0] = p0; o[1] = p1;
  *(u32x2*)(out + ((size_t)row << 10) + (tid << 2)) = o;
}

// ---------------- weight transpose: f32 [R][C] -> bf16 [C][R] ----------------
__global__ __launch_bounds__(256) void transp_k(const float* __restrict__ in,
    unsigned short* __restrict__ out, int R, int C) {
  __shared__ unsigned short tile[64 * 65];
  size_t lay = (size_t)blockIdx.z * R * C;
  int c0 = blockIdx.x << 6, r0 = blockIdx.y << 6;
  int t = threadIdx.x;
  #pragma unroll
  for (int i = 0; i < 4; i++) {
    int e = (i << 10) + (t << 2);
    int r = e >> 6, c = e & 63;
    f32x4 v = *(const f32x4*)(in + lay + (size_t)(r0 + r) * C + c0 + c);
    tile[r * 65 + c]     = f2bf(v[0]);
    tile[r * 65 + c + 1] = f2bf(v[1]);
    tile[r * 65 + c + 2] = f2bf(v[2]);
    tile[r * 65 + c + 3] = f2bf(v[3]);
  }
  __syncthreads();
  #pragma unroll
  for (int i = 0; i < 4; i++) {
    int e = (i << 10) + (t << 2);
    int cc = e >> 6, rr = e & 63;
    unsigned int a0 = tile[(rr + 0) * 65 + cc];
    unsigned int a1 = tile[(rr + 1) * 65 + cc];
    unsigned int a2 = tile[(rr + 2) * 65 + cc];
    unsigned int a3 = tile[(rr + 3) * 65 + cc];
    u32x2 pk; pk[0] = a0 | (a1 << 16); pk[1] = a2 | (a3 << 16);
    *(u32x2*)(out + lay + (size_t)(c0 + cc) * R + r0 + rr) = pk;
  }
}

// ============ 256x256 8-phase-family GEMM (T2+T3+T4+T5), plain HIP ============
// A bf16 [M][K], Bt bf16 [N][K]. 512 thr = 8 waves (2M x 4N). BK=64.
// LDS 128KB: [op][buf][half][128*64] shorts, XOR-swizzled (kbyte16 ^= row&7).
// 4 phases per K-tile, one (A-half,B-half) quadrant each: 12 ds_read_b128 +
// 16 MFMA. Pair-staging at q0/q1 (4 gload_lds), counted vmcnt(4) at q0/q3 end.
#define VMC4 asm volatile("s_waitcnt vmcnt(4)" ::: "memory")

__global__ __launch_bounds__(512, 2) void gemm256_k(
    const unsigned short* __restrict__ A, const unsigned short* __restrict__ Bt,
    const float* __restrict__ bias, float* __restrict__ o32,
    unsigned short* __restrict__ obf, int M, int N, int K, int relu) {
  __shared__ unsigned short lds[2][2][2][8192];
  int nb = N >> 8;
  int wg = blockIdx.x, nwg = gridDim.x;
  int cpx = nwg >> 3;
  int swz = (wg & 7) * cpx + (wg >> 3);      // nwg % 8 == 0
  int bm = swz / nb, bn = swz - bm * nb;
  int m0 = bm << 8, n0 = bn << 8;
  int tid = threadIdx.x, lane = tid & 63, wave = tid >> 6;
  int wrow = wave >> 2, wcol = wave & 3;
  int lrow = lane & 15, g4 = lane >> 4, l7 = lane & 7;
  f32x4 acc[8][4] = {};
  const unsigned short* Ag = A + (size_t)m0 * K;
  const unsigned short* Bg = Bt + (size_t)n0 * K;
  // stage half h (128 rows x 64 k) of op into buf b at k-offset kt.
  // linear LDS dest (wave-uniform base), inverse-swizzled global source.
  auto stage = [&](int op, int b, int h, int kt) {
    const unsigned short* gb = (op ? Bg : Ag) + ((size_t)(h << 7)) * K + kt;
    char* lb = (char*)&lds[op][b][h][0];
    #pragma unroll
    for (int g = 0; g < 2; g++) {
      int row = (g << 6) + (wave << 3) + (lane >> 3);
      int klog = ((lane & 7) ^ ((lane >> 3) & 7)) << 3;   // shorts
      gload16(gb + (size_t)row * K + klog, lb + (g << 13) + (wave << 10));
    }
  };

#define PH(qa, qb, STG, VM)                                                    \
  {                                                                            \
    const unsigned short* Ah = &lds[0][buf][qa][0];                            \
    const unsigned short* Bh = &lds[1][buf][qb][0];                            \
    bf16x8 af[8], bfv[4];                                                      \
    _Pragma("unroll")                                                          \
    for (int i = 0; i < 4; i++) {                                              \
      int rl = (wrow << 6) + (i << 4) + lrow;                                  \
      af[i*2+0] = *(const bf16x8*)(Ah + rl * 64 + ((g4 ^ l7) << 3));           \
      af[i*2+1] = *(const bf16x8*)(Ah + rl * 64 + (((4 + g4) ^ l7) << 3));     \
    }                                                                          \
    _Pragma("unroll")                                                          \
    for (int j = 0; j < 2; j++) {                                              \
      int cl = (wcol << 5) + (j << 4) + lrow;                                  \
      bfv[j*2+0] = *(const bf16x8*)(Bh + cl * 64 + ((g4 ^ l7) << 3));          \
      bfv[j*2+1] = *(const bf16x8*)(Bh + cl * 64 + (((4 + g4) ^ l7) << 3));    \
    }                                                                          \
    STG;                                                                       \
    __builtin_amdgcn_s_barrier();                                              \
    asm volatile("s_waitcnt lgkmcnt(0)" ::: "memory");                         \
    __builtin_amdgcn_sched_barrier(0);                                         \
    __builtin_amdgcn_s_setprio(1);                                             \
    _Pragma("unroll")                                                          \
    for (int i = 0; i < 4; i++)                                                \
      _Pragma("unroll")                                                        \
      for (int j = 0; j < 2; j++) {                                            \
        acc[(qa)*4+i][(qb)*2+j] = __builtin_amdgcn_mfma_f32_16x16x32_bf16(     \
            af[i*2+0], bfv[j*2+0], acc[(qa)*4+i][(qb)*2+j], 0, 0, 0);          \
        acc[(qa)*4+i][(qb)*2+j] = __builtin_amdgcn_mfma_f32_16x16x32_bf16(     \
            af[i*2+1], bfv[j*2+1], acc[(qa)*4+i][(qb)*2+j], 0, 0, 0);          \
      }                                                                        \
    __builtin_amdgcn_s_setprio(0);                                             \
    VM;                                                                        \
    __builtin_amdgcn_s_barrier();                                              \
  }

  int nt = K >> 6;
  // prologue: tile0 -> buf0 (A0,B0 then A1,B1); wait for A0,B0.
  stage(0, 0, 0, 0); stage(1, 0, 0, 0);
  stage(0, 0, 1, 0); stage(1, 0, 1, 0);
  VMC4;
  __builtin_amdgcn_s_barrier();
  for (int t = 0; t < nt; ++t) {
    int buf = t & 1, nxt = buf ^ 1;
    int kt = (t + 1) << 6;
    bool more = (t + 1) < nt;
    PH(0, 0, if (more) { stage(0, nxt, 0, kt); stage(1, nxt, 0, kt); }, VMC4)
    PH(1, 0, if (more) { stage(0, nxt, 1, kt); stage(1, nxt, 1, kt); }, )
    PH(0, 1, , )
    PH(1, 1, , VMC4)
  }
#undef PH
  int frow = g4 << 2;
  #pragma unroll
  for (int rt = 0; rt < 8; rt++) {
    int qa = rt >> 2, i = rt & 3;
    int grow = m0 + (qa << 7) + (wrow << 6) + (i << 4) + frow;
    #pragma unroll
    for (int ct = 0; ct < 4; ct++) {
      int qb = ct >> 1, j = ct & 1;
      int gcol = n0 + (qb << 7) + (wcol << 5) + (j << 4) + lrow;
      float bb = bias ? bias[gcol] : 0.f;
      f32x4 av = acc[rt][ct];
      #pragma unroll
      for (int r = 0; r < 4; r++) {
        float vv = av[r] + bb;
        if (relu) vv = fmaxf(vv, 0.f);
        if (o32) o32[(size_t)(grow + r) * N + gcol] = vv;
        else obf[(size_t)(grow + r) * N + gcol] = f2bf(vv);
      }
    }
  }
}

// ---------------- m97-structure GEMM (layer GEMMs) ----------------
__global__ __launch_bounds__(256) void gemm_bt(
    const unsigned short* __restrict__ A,
    const unsigned short* __restrict__ Bt0, const unsigned short* __restrict__ Bt1,
    const unsigned short* __restrict__ Bt2,
    const float* __restrict__ bias, const float* resid,
    unsigned short* __restrict__ ob0, unsigned short* __restrict__ ob1,
    unsigned short* __restrict__ vtout, float* o32,
    int M, int N, int K, int relu) {
  __shared__ unsigned short As[128 * 64];
  __shared__ unsigned short Bs[128 * 64];
  int nbp = N >> 7;
  int which = blockIdx.x / nbp;
  int bx = blockIdx.x - which * nbp;
  const unsigned short* Bt = which == 0 ? Bt0 : (which == 1 ? Bt1 : Bt2);
  int m0 = blockIdx.y << 7, n0 = bx << 7;
  int tid = threadIdx.x, lane = tid & 63, wave = tid >> 6;
  int wr = (wave >> 1) << 6, wc = (wave & 1) << 6;
  int lrow = lane & 15, lk8 = (lane >> 4) << 3;
  int wbase = wave << 12;
  f32x4 acc[4][4] = {};
  const unsigned short* Ag = A + (size_t)m0 * K;
  const unsigned short* Bg = Bt + (size_t)n0 * K;
  for (int k0 = 0; k0 < K; k0 += 64) {
    #pragma unroll
    for (int i = 0; i < 4; i++) {
      int o = wbase + (i << 10) + (lane << 4);
      int r = o >> 7, c = (o & 127) >> 1;
      gload16(Ag + (size_t)r * K + k0 + c, (char*)As + wbase + (i << 10));
      gload16(Bg + (size_t)r * K + k0 + c, (char*)Bs + wbase + (i << 10));
    }
    __syncthreads();
    #pragma unroll
    for (int ks = 0; ks < 2; ks++) {
      bf16x8 af[4], bfv[4];
      #pragma unroll
      for (int i = 0; i < 4; i++)
        af[i] = *(const bf16x8*)(As + ((wr + (i << 4) + lrow) << 6) + (ks << 5) + lk8);
      #pragma unroll
      for (int i = 0; i < 4; i++)
        bfv[i] = *(const bf16x8*)(Bs + ((wc + (i << 4) + lrow) << 6) + (ks << 5) + lk8);
      #pragma unroll
      for (int mi = 0; mi < 4; mi++)
        #pragma unroll
        for (int ni = 0; ni < 4; ni++)
          acc[mi][ni] = __builtin_amdgcn_mfma_f32_16x16x32_bf16(af[mi], bfv[ni], acc[mi][ni], 0, 0, 0);
    }
    __syncthreads();
  }
  int fr = (lane >> 4) << 2;
  #pragma unroll
  for (int mi = 0; mi < 4; mi++) {
    #pragma unroll
    for (int ni = 0; ni < 4; ni++) {
      int row = m0 + wr + (mi << 4) + fr;
      int col = n0 + wc + (ni << 4) + lrow;
      f32x4 av = acc[mi][ni];
      if (bias) {
        float bb = bias[col];
        av[0] += bb; av[1] += bb; av[2] += bb; av[3] += bb;
      }
      if (relu) {
        av[0] = fmaxf(av[0], 0.f); av[1] = fmaxf(av[1], 0.f);
        av[2] = fmaxf(av[2], 0.f); av[3] = fmaxf(av[3], 0.f);
      }
      if (which == 2) {
        u32x2 pk;
        pk[0] = (unsigned int)f2bf(av[0]) | ((unsigned int)f2bf(av[1]) << 16);
        pk[1] = (unsigned int)f2bf(av[2]) | ((unsigned int)f2bf(av[3]) << 16);
        *(u32x2*)(vtout + (((size_t)(row >> 10) * 16 + (col >> 6)) * 64 + (col & 63)) * 1024
                  + (row & 1023)) = pk;
      } else if (o32) {
        #pragma unroll
        for (int r = 0; r < 4; r++) {
          size_t off = (size_t)(row + r) * N + col;
          float vvv = av[r];
          if (resid) vvv += resid[off];
          o32[off] = vvv;
        }
      } else {
        unsigned short* ob = which == 0 ? ob0 : ob1;
        #pragma unroll
        for (int r = 0; r < 4; r++)
          ob[(size_t)(row + r) * N + col] = f2bf(av[r]);
      }
    }
  }
}

// ---------------- windowed flash attention, 4 waves/block ----------------
__global__ __launch_bounds__(256) void attn4_k(
    const unsigned short* __restrict__ q, const unsigned short* __restrict__ k,
    const unsigned short* __restrict__ vt, unsigned short* __restrict__ att) {
  __shared__ unsigned short Ks[32 * 72];
  __shared__ unsigned short Vt[64 * 40];
  __shared__ unsigned short Ps[4][16 * 40];
  int t0 = blockIdx.x << 6;
  int h = blockIdx.y, b = blockIdx.z;
  int tid = threadIdx.x, lane = tid & 63, w = tid >> 6;
  int lrow = lane & 15, lk8 = (lane >> 4) << 3, fr = (lane >> 4) << 2;
  int qrow = t0 + (w << 4) + lrow;
  size_t qoff = ((size_t)((b << 10) + qrow) << 10) + (h << 6);
  bf16x8 a0 = *(const bf16x8*)(q + qoff + lk8);
  bf16x8 a1 = *(const bf16x8*)(q + qoff + 32 + lk8);
  float m_[4] = {-1e30f, -1e30f, -1e30f, -1e30f};
  float l_[4] = {0.f, 0.f, 0.f, 0.f};
  f32x4 o_[4] = {};
  int s_lo = (511 - ((t0 + 63) >> 1)) & ~31;
  int s_hi = 511 + ((t0 + 64) >> 1);
  int s_end = (s_hi + 32) & ~31;
  int krow = tid >> 3, ks0 = (tid & 7) << 3;
  int vd = tid >> 2, vs0 = (tid & 3) << 3;
  size_t vbase = ((size_t)((b << 4) + h) << 16) + ((size_t)vd << 10);
  unsigned short* Psw = &Ps[w][0];
  for (int s0 = s_lo; s0 < s_end; s0 += 32) {
    u32x4 kv = *(const u32x4*)(k + (((size_t)((b << 10) + s0 + krow)) << 10) + (h << 6) + ks0);
    u32x4 vv = *(const u32x4*)(vt + vbase + s0 + vs0);
    *(u32x4*)(Ks + krow * 72 + ks0) = kv;
    *(u32x4*)(Vt + vd * 40 + vs0) = vv;
    __syncthreads();
    f32x4 sc0 = {}, sc1 = {};
    {
      bf16x8 kb0 = *(const bf16x8*)(Ks + lrow * 72 + lk8);
      bf16x8 kb1 = *(const bf16x8*)(Ks + lrow * 72 + 32 + lk8);
      sc0 = __builtin_amdgcn_mfma_f32_16x16x32_bf16(a0, kb0, sc0, 0, 0, 0);
      sc0 = __builtin_amdgcn_mfma_f32_16x16x32_bf16(a1, kb1, sc0, 0, 0, 0);
      bf16x8 kb2 = *(const bf16x8*)(Ks + (16 + lrow) * 72 + lk8);
      bf16x8 kb3 = *(const bf16x8*)(Ks + (16 + lrow) * 72 + 32 + lk8);
      sc1 = __builtin_amdgcn_mfma_f32_16x16x32_bf16(a0, kb2, sc1, 0, 0, 0);
      sc1 = __builtin_amdgcn_mfma_f32_16x16x32_bf16(a1, kb3, sc1, 0, 0, 0);
    }
    #pragma unroll
    for (int r = 0; r < 4; r++) {
      int t = t0 + (w << 4) + fr + r;
      int lov = 511 - (t >> 1), hiv = 511 + ((t + 1) >> 1);
      int sA = s0 + lrow, sB = sA + 16;
      bool vA = (sA >= lov) && (sA <= hiv);
      bool vB = (sB >= lov) && (sB <= hiv);
      float xA = vA ? sc0[r] * 0.125f : -1e30f;
      float xB = vB ? sc1[r] * 0.125f : -1e30f;
      float tm = fmaxf(xA, xB);
      #pragma unroll
      for (int off = 8; off; off >>= 1) tm = fmaxf(tm, __shfl_xor(tm, off));
      float nm = fmaxf(m_[r], tm);
      float pA = vA ? __expf(xA - nm) : 0.f;
      float pB = vB ? __expf(xB - nm) : 0.f;
      float sca = __expf(m_[r] - nm);
      m_[r] = nm;
      float ps = pA + pB;
      #pragma unroll
      for (int off = 8; off; off >>= 1) ps += __shfl_xor(ps, off);
      l_[r] = l_[r] * sca + ps;
      #pragma unroll
      for (int nb = 0; nb < 4; nb++) o_[nb][r] *= sca;
      Psw[(fr + r) * 40 + lrow]      = f2bf(pA);
      Psw[(fr + r) * 40 + 16 + lrow] = f2bf(pB);
    }
    bf16x8 pa = *(const bf16x8*)(Psw + lrow * 40 + lk8);
    #pragma unroll
    for (int nb = 0; nb < 4; nb++) {
      bf16x8 vb_ = *(const bf16x8*)(Vt + ((nb << 4) + lrow) * 40 + lk8);
      o_[nb] = __builtin_amdgcn_mfma_f32_16x16x32_bf16(pa, vb_, o_[nb], 0, 0, 0);
    }
    __syncthreads();
  }
  #pragma unroll
  for (int nb = 0; nb < 4; nb++)
    #pragma unroll
    for (int r = 0; r < 4; r++) {
      float ov = o_[nb][r] / l_[r];
      att[((size_t)((b << 10) + t0 + (w << 4) + fr + r) << 10) + (h << 6) + (nb << 4) + lrow]
          = f2bf(ov);
    }
}

extern "C" void kernel_launch(void* const* d_in, const int* in_sizes, int n_in,
                              void* d_out, int out_size, void* d_ws, size_t ws_size,
                              hipStream_t stream) {
  (void)in_sizes; (void)n_in; (void)out_size;
  const int*   idx  = (const int*)d_in[0];
  const float* tok  = (const float*)d_in[1];
  const float* pos  = (const float*)d_in[2];
  const float* ln1g = (const float*)d_in[3];
  const float* ln1b = (const float*)d_in[4];
  const float* wq   = (const float*)d_in[5];
  const float* wk   = (const float*)d_in[6];
  const float* wv   = (const float*)d_in[7];
  const float* wpj  = (const float*)d_in[8];
  const float* bpj  = (const float*)d_in[9];
  const float* ln2g = (const float*)d_in[10];
  const float* ln2b = (const float*)d_in[11];
  const float* w1   = (const float*)d_in[12];
  const float* b1   = (const float*)d_in[13];
  const float* w2   = (const float*)d_in[14];
  const float* b2   = (const float*)d_in[15];
  const float* lnfg = (const float*)d_in[16];
  const float* lnfb = (const float*)d_in[17];
  const float* wlm  = (const float*)d_in[18];
  const float* blm  = (const float*)d_in[19];
  float* out = (float*)d_out;

  char* ws = (char*)d_ws;
  const size_t MB = 1u << 20;
  float*          x    = (float*)ws;
  unsigned short* hb   = (unsigned short*)(ws + 8 * MB);
  unsigned short* qb   = (unsigned short*)(ws + 12 * MB);
  unsigned short* kb   = (unsigned short*)(ws + 16 * MB);
  unsigned short* vbuf = (unsigned short*)(ws + 20 * MB);
  unsigned short* ab   = (unsigned short*)(ws + 24 * MB);
  unsigned short* m1   = (unsigned short*)(ws + 28 * MB);
  const int M = 2048, D = 1024;

  embed_k<<<dim3(2048), dim3(256), 0, stream>>>(idx, tok, pos, x);

  unsigned short* wqT  = (unsigned short*)(ws + 44 * MB);
  unsigned short* wkT  = (unsigned short*)(ws + 60 * MB);
  unsigned short* wvT  = (unsigned short*)(ws + 76 * MB);
  unsigned short* wpT  = (unsigned short*)(ws + 92 * MB);
  unsigned short* w1T  = (unsigned short*)(ws + 108 * MB);
  unsigned short* w2T  = (unsigned short*)(ws + 172 * MB);
  unsigned short* wlmT = (unsigned short*)(ws + 236 * MB);
  transp_k<<<dim3(16, 16, 8), 256, 0, stream>>>(wq,   wqT,  1024, 1024);
  transp_k<<<dim3(16, 16, 8), 256, 0, stream>>>(wk,   wkT,  1024, 1024);
  transp_k<<<dim3(16, 16, 8), 256, 0, stream>>>(wv,   wvT,  1024, 1024);
  transp_k<<<dim3(16, 16, 8), 256, 0, stream>>>(wpj,  wpT,  1024, 1024);
  transp_k<<<dim3(64, 16, 8), 256, 0, stream>>>(w1,   w1T,  1024, 4096);
  transp_k<<<dim3(16, 64, 8), 256, 0, stream>>>(w2,   w2T,  4096, 1024);
  transp_k<<<dim3(1000, 16, 1), 256, 0, stream>>>(wlm, wlmT, 1024, 64000);
  for (int l = 0; l < 8; l++) {
    size_t wo = (size_t)l << 20;
    ln_k<<<2048, 256, 0, stream>>>(x, ln1g + l*D, ln1b + l*D, hb);
    gemm_bt<<<dim3(24, 16), 256, 0, stream>>>(hb, wqT + wo, wkT + wo, wvT + wo,
        nullptr, nullptr, qb, kb, vbuf, nullptr, M, D, D, 0);
    attn4_k<<<dim3(16, 16, 2), 256, 0, stream>>>(qb, kb, vbuf, ab);
    gemm_bt<<<dim3(8, 16), 256, 0, stream>>>(ab, wpT + wo, nullptr, nullptr,
        bpj + l*D, x, nullptr, nullptr, nullptr, x, M, D, D, 0);
    ln_k<<<2048, 256, 0, stream>>>(x, ln2g + l*D, ln2b + l*D, hb);
    gemm256_k<<<dim3(128), 512, 0, stream>>>(hb, w1T + ((size_t)l << 22),
        b1 + (size_t)l*4*D, nullptr, m1, M, 4*D, D, 1);
    gemm_bt<<<dim3(8, 16), 256, 0, stream>>>(m1, w2T + ((size_t)l << 22), nullptr, nullptr,
        b2 + l*D, x, nullptr, nullptr, nullptr, x, M, D, 4*D, 0);
  }
  ln_k<<<2048, 256, 0, stream>>>(x, lnfg, lnfb, hb);
  gemm256_k<<<dim3(2000), 512, 0, stream>>>(hb, wlmT,
      blm, out, nullptr, M, 64000, D, 0);
}

// Round 6
// 2877.529 us; speedup vs baseline: 1.5319x; 1.0215x over previous
//
#include <hip/hip_runtime.h>

typedef __attribute__((ext_vector_type(8))) __bf16 bf16x8;
typedef __attribute__((ext_vector_type(4))) float f32x4;
typedef __attribute__((ext_vector_type(4))) unsigned int u32x4;
typedef __attribute__((ext_vector_type(2))) unsigned int u32x2;

__device__ __forceinline__ unsigned short f2bf(float f) {
  unsigned int u = __float_as_uint(f);
  u += 0x7fffu + ((u >> 16) & 1u);   // RNE
  return (unsigned short)(u >> 16);
}

__device__ __forceinline__ void gload16(const void* g, void* l) {
  __builtin_amdgcn_global_load_lds(
      (const __attribute__((address_space(1))) unsigned int*)g,
      (__attribute__((address_space(3))) unsigned int*)l, 16, 0, 0);
}

// ---------------- embedding ----------------
__global__ __launch_bounds__(256) void embed_k(const int* __restrict__ idx,
    const float* __restrict__ tok, const float* __restrict__ pos,
    float* __restrict__ x) {
  int row = blockIdx.x;
  int t = row & 1023;
  int c = threadIdx.x << 2;
  int id = idx[row];
  f32x4 a = *(const f32x4*)(tok + ((size_t)id << 10) + c);
  f32x4 p = *(const f32x4*)(pos + ((size_t)t << 10) + c);
  a += p;
  *(f32x4*)(x + ((size_t)row << 10) + c) = a;
}

// ---------------- layernorm (f32 in, bf16 out) ----------------
__global__ __launch_bounds__(256) void ln_k(const float* __restrict__ x,
    const float* __restrict__ g, const float* __restrict__ bta,
    unsigned short* __restrict__ out) {
  __shared__ float red[4];
  int row = blockIdx.x, tid = threadIdx.x;
  const float* xr = x + ((size_t)row << 10);
  f32x4 xv = *(const f32x4*)(xr + (tid << 2));
  float s = xv[0] + xv[1] + xv[2] + xv[3];
  #pragma unroll
  for (int off = 32; off; off >>= 1) s += __shfl_xor(s, off);
  if ((tid & 63) == 0) red[tid >> 6] = s;
  __syncthreads();
  float mean = (red[0] + red[1] + red[2] + red[3]) * (1.f / 1024.f);
  __syncthreads();
  f32x4 d = xv - mean;
  float s2 = d[0]*d[0] + d[1]*d[1] + d[2]*d[2] + d[3]*d[3];
  #pragma unroll
  for (int off = 32; off; off >>= 1) s2 += __shfl_xor(s2, off);
  if ((tid & 63) == 0) red[tid >> 6] = s2;
  __syncthreads();
  float var = (red[0] + red[1] + red[2] + red[3]) * (1.f / 1024.f);
  float rs = rsqrtf(var + 1e-5f);
  f32x4 gv = *(const f32x4*)(g + (tid << 2));
  f32x4 bv = *(const f32x4*)(bta + (tid << 2));
  unsigned int p0 = (unsigned int)f2bf(d[0]*rs*gv[0] + bv[0]) |
                    ((unsigned int)f2bf(d[1]*rs*gv[1] + bv[1]) << 16);
  unsigned int p1 = (unsigned int)f2bf(d[2]*rs*gv[2] + bv[2]) |
                    ((unsigned int)f2bf(d[3]*rs*gv[3] + bv[3]) << 16);
  u32x2 o; o[0] = p0; o[1] = p1;
  *(u32x2*)(out + ((size_t)row << 10) + (tid << 2)) = o;
}

// ---------------- weight transpose: f32 [R][C] -> bf16 [C][R] ----------------
__global__ __launch_bounds__(256) void transp_k(const float* __restrict__ in,
    unsigned short* __restrict__ out, int R, int C) {
  __shared__ unsigned short tile[64 * 65];
  size_t lay = (size_t)blockIdx.z * R * C;
  int c0 = blockIdx.x << 6, r0 = blockIdx.y << 6;
  int t = threadIdx.x;
  #pragma unroll
  for (int i = 0; i < 4; i++) {
    int e = (i << 10) + (t << 2);
    int r = e >> 6, c = e & 63;
    f32x4 v = *(const f32x4*)(in + lay + (size_t)(r0 + r) * C + c0 + c);
    tile[r * 65 + c]     = f2bf(v[0]);
    tile[r * 65 + c + 1] = f2bf(v[1]);
    tile[r * 65 + c + 2] = f2bf(v[2]);
    tile[r * 65 + c + 3] = f2bf(v[3]);
  }
  __syncthreads();
  #pragma unroll
  for (int i = 0; i < 4; i++) {
    int e = (i << 10) + (t << 2);
    int cc = e >> 6, rr = e & 63;
    unsigned int a0 = tile[(rr + 0) * 65 + cc];
    unsigned int a1 = tile[(rr + 1) * 65 + cc];
    unsigned int a2 = tile[(rr + 2) * 65 + cc];
    unsigned int a3 = tile[(rr + 3) * 65 + cc];
    u32x2 pk; pk[0] = a0 | (a1 << 16); pk[1] = a2 | (a3 << 16);
    *(u32x2*)(out + lay + (size_t)(c0 + cc) * R + r0 + rr) = pk;
  }
}

// ============ 256x256 8-phase GEMM (m201 schedule: T2+T3+T4+T5) ============
// A bf16 [M][K], Bt bf16 [N][K]. 512 thr = 8 waves (2M x 4N). BK=64.
// 2 K-tiles/iter (buf0=even, buf1=odd), 8 phases, ONE half-tile stage (2
// gload_lds) per phase, vmcnt(4) at p4/p8 in steady state.
// TAIL FIX (r5 bug): last iteration has no p3/p4 stages, so only 8 loads are
// outstanding at p4 -> vmcnt(4) left buf1.{B1,A1} in flight for p6-p8 reads.
// Last iteration p4 must drain with vmcnt(0). K%128==0 required.
#define VMC4 asm volatile("s_waitcnt vmcnt(4)" ::: "memory")
#define VMC0 asm volatile("s_waitcnt vmcnt(0)" ::: "memory")

__global__ __launch_bounds__(512, 2) void gemm256_k(
    const unsigned short* __restrict__ A, const unsigned short* __restrict__ Bt,
    const float* __restrict__ bias, float* __restrict__ o32,
    unsigned short* __restrict__ obf, int M, int N, int K, int relu) {
  __shared__ unsigned short lds[2][2][2][8192];
  int nb = N >> 8;
  int wg = blockIdx.x, nwg = gridDim.x;
  int cpx = nwg >> 3;
  int swz = (wg & 7) * cpx + (wg >> 3);      // nwg % 8 == 0
  int bm = swz / nb, bn = swz - bm * nb;
  int m0 = bm << 8, n0 = bn << 8;
  int tid = threadIdx.x, lane = tid & 63, wave = tid >> 6;
  int wrow = wave >> 2, wcol = wave & 3;
  int lrow = lane & 15, g4 = lane >> 4, l7 = lane & 7;
  f32x4 acc[8][4] = {};
  const unsigned short* Ag = A + (size_t)m0 * K;
  const unsigned short* Bg = Bt + (size_t)n0 * K;
  // stage half h (128 rows x 64 k) of op into buf b at k-offset kt.
  // linear LDS dest (wave-uniform base), inverse-swizzled global source.
  auto stage = [&](int op, int b, int h, int kt) {
    const unsigned short* gb = (op ? Bg : Ag) + ((size_t)(h << 7)) * K + kt;
    char* lb = (char*)&lds[op][b][h][0];
    #pragma unroll
    for (int g = 0; g < 2; g++) {
      int row = (g << 6) + (wave << 3) + (lane >> 3);
      int klog = ((lane & 7) ^ ((lane >> 3) & 7)) << 3;   // shorts
      gload16(gb + (size_t)row * K + klog, lb + (g << 13) + (wave << 10));
    }
  };

#define PH(bi, qa, qb, STG, VM)                                                \
  {                                                                            \
    const unsigned short* Ah = &lds[0][bi][qa][0];                             \
    const unsigned short* Bh = &lds[1][bi][qb][0];                             \
    bf16x8 af[8], bfv[4];                                                      \
    _Pragma("unroll")                                                          \
    for (int i = 0; i < 4; i++) {                                              \
      int rl = (wrow << 6) + (i << 4) + lrow;                                  \
      af[i*2+0] = *(const bf16x8*)(Ah + rl * 64 + ((g4 ^ l7) << 3));           \
      af[i*2+1] = *(const bf16x8*)(Ah + rl * 64 + (((4 + g4) ^ l7) << 3));     \
    }                                                                          \
    _Pragma("unroll")                                                          \
    for (int j = 0; j < 2; j++) {                                              \
      int cl = (wcol << 5) + (j << 4) + lrow;                                  \
      bfv[j*2+0] = *(const bf16x8*)(Bh + cl * 64 + ((g4 ^ l7) << 3));          \
      bfv[j*2+1] = *(const bf16x8*)(Bh + cl * 64 + (((4 + g4) ^ l7) << 3));    \
    }                                                                          \
    STG;                                                                       \
    __builtin_amdgcn_s_barrier();                                              \
    asm volatile("s_waitcnt lgkmcnt(0)" ::: "memory");                         \
    __builtin_amdgcn_sched_barrier(0);                                         \
    __builtin_amdgcn_s_setprio(1);                                             \
    _Pragma("unroll")                                                          \
    for (int i = 0; i < 4; i++)                                                \
      _Pragma("unroll")                                                        \
      for (int j = 0; j < 2; j++) {                                            \
        acc[(qa)*4+i][(qb)*2+j] = __builtin_amdgcn_mfma_f32_16x16x32_bf16(     \
            af[i*2+0], bfv[j*2+0], acc[(qa)*4+i][(qb)*2+j], 0, 0, 0);          \
        acc[(qa)*4+i][(qb)*2+j] = __builtin_amdgcn_mfma_f32_16x16x32_bf16(     \
            af[i*2+1], bfv[j*2+1], acc[(qa)*4+i][(qb)*2+j], 0, 0, 0);          \
      }                                                                        \
    __builtin_amdgcn_s_setprio(0);                                             \
    VM;                                                                        \
    __builtin_amdgcn_s_barrier();                                              \
  }

  int nt = K >> 6;          // K-tiles; nt even (K%128==0)
  int nit = nt >> 1;        // iterations, 2 tiles each
  // prologue: buf0 <- tile0 (4 half-tiles), buf1 <- tile1 {A0,B0}.
  // invariant entering each iteration: outstanding = {buf1.A0,B0} (4 loads).
  stage(0, 0, 0, 0); stage(1, 0, 0, 0); stage(1, 0, 1, 0); stage(0, 0, 1, 0);
  stage(0, 1, 0, 64); stage(1, 1, 0, 64);
  VMC4;                     // buf0 resident; buf1.A0,B0 in flight
  __builtin_amdgcn_s_barrier();
  for (int it = 0; it < nit; ++it) {
    int kT1 = ((it << 1) + 1) << 6;
    int kT2 = ((it << 1) + 2) << 6;
    int kT3 = ((it << 1) + 3) << 6;
    bool m2 = (it + 1) < nit;   // tiles T+2, T+3 exist
    PH(0, 0, 0, { stage(1, 1, 1, kT1); }, )                 // p1: buf1.B1<-T+1
    PH(0, 0, 1, { stage(0, 1, 1, kT1); }, )                 // p2: buf1.A1<-T+1
    PH(0, 1, 0, if (m2) { stage(0, 0, 0, kT2); }, )         // p3: buf0.A0<-T+2
    PH(0, 1, 1, if (m2) { stage(1, 0, 0, kT2); },           // p4: buf0.B0<-T+2
       if (m2) { VMC4; } else { VMC0; })                    //   tail: full drain
    PH(1, 0, 0, if (m2) { stage(1, 0, 1, kT2); }, )         // p5: buf0.B1<-T+2
    PH(1, 0, 1, if (m2) { stage(0, 0, 1, kT2); }, )         // p6: buf0.A1<-T+2
    PH(1, 1, 0, if (m2) { stage(0, 1, 0, kT3); }, )         // p7: buf1.A0<-T+3
    PH(1, 1, 1, if (m2) { stage(1, 1, 0, kT3); }, VMC4)     // p8: buf1.B0<-T+3
  }
#undef PH
  int frow = g4 << 2;
  #pragma unroll
  for (int rt = 0; rt < 8; rt++) {
    int qa = rt >> 2, i = rt & 3;
    int grow = m0 + (qa << 7) + (wrow << 6) + (i << 4) + frow;
    #pragma unroll
    for (int ct = 0; ct < 4; ct++) {
      int qb = ct >> 1, j = ct & 1;
      int gcol = n0 + (qb << 7) + (wcol << 5) + (j << 4) + lrow;
      float bb = bias ? bias[gcol] : 0.f;
      f32x4 av = acc[rt][ct];
      #pragma unroll
      for (int r = 0; r < 4; r++) {
        float vv = av[r] + bb;
        if (relu) vv = fmaxf(vv, 0.f);
        if (o32) o32[(size_t)(grow + r) * N + gcol] = vv;
        else obf[(size_t)(grow + r) * N + gcol] = f2bf(vv);
      }
    }
  }
}

// ---------------- m97-structure GEMM (layer GEMMs) ----------------
__global__ __launch_bounds__(256) void gemm_bt(
    const unsigned short* __restrict__ A,
    const unsigned short* __restrict__ Bt0, const unsigned short* __restrict__ Bt1,
    const unsigned short* __restrict__ Bt2,
    const float* __restrict__ bias, const float* resid,
    unsigned short* __restrict__ ob0, unsigned short* __restrict__ ob1,
    unsigned short* __restrict__ vtout, float* o32,
    int M, int N, int K, int relu) {
  __shared__ unsigned short As[128 * 64];
  __shared__ unsigned short Bs[128 * 64];
  int nbp = N >> 7;
  int which = blockIdx.x / nbp;
  int bx = blockIdx.x - which * nbp;
  const unsigned short* Bt = which == 0 ? Bt0 : (which == 1 ? Bt1 : Bt2);
  int m0 = blockIdx.y << 7, n0 = bx << 7;
  int tid = threadIdx.x, lane = tid & 63, wave = tid >> 6;
  int wr = (wave >> 1) << 6, wc = (wave & 1) << 6;
  int lrow = lane & 15, lk8 = (lane >> 4) << 3;
  int wbase = wave << 12;
  f32x4 acc[4][4] = {};
  const unsigned short* Ag = A + (size_t)m0 * K;
  const unsigned short* Bg = Bt + (size_t)n0 * K;
  for (int k0 = 0; k0 < K; k0 += 64) {
    #pragma unroll
    for (int i = 0; i < 4; i++) {
      int o = wbase + (i << 10) + (lane << 4);
      int r = o >> 7, c = (o & 127) >> 1;
      gload16(Ag + (size_t)r * K + k0 + c, (char*)As + wbase + (i << 10));
      gload16(Bg + (size_t)r * K + k0 + c, (char*)Bs + wbase + (i << 10));
    }
    __syncthreads();
    #pragma unroll
    for (int ks = 0; ks < 2; ks++) {
      bf16x8 af[4], bfv[4];
      #pragma unroll
      for (int i = 0; i < 4; i++)
        af[i] = *(const bf16x8*)(As + ((wr + (i << 4) + lrow) << 6) + (ks << 5) + lk8);
      #pragma unroll
      for (int i = 0; i < 4; i++)
        bfv[i] = *(const bf16x8*)(Bs + ((wc + (i << 4) + lrow) << 6) + (ks << 5) + lk8);
      #pragma unroll
      for (int mi = 0; mi < 4; mi++)
        #pragma unroll
        for (int ni = 0; ni < 4; ni++)
          acc[mi][ni] = __builtin_amdgcn_mfma_f32_16x16x32_bf16(af[mi], bfv[ni], acc[mi][ni], 0, 0, 0);
    }
    __syncthreads();
  }
  int fr = (lane >> 4) << 2;
  #pragma unroll
  for (int mi = 0; mi < 4; mi++) {
    #pragma unroll
    for (int ni = 0; ni < 4; ni++) {
      int row = m0 + wr + (mi << 4) + fr;
      int col = n0 + wc + (ni << 4) + lrow;
      f32x4 av = acc[mi][ni];
      if (bias) {
        float bb = bias[col];
        av[0] += bb; av[1] += bb; av[2] += bb; av[3] += bb;
      }
      if (relu) {
        av[0] = fmaxf(av[0], 0.f); av[1] = fmaxf(av[1], 0.f);
        av[2] = fmaxf(av[2], 0.f); av[3] = fmaxf(av[3], 0.f);
      }
      if (which == 2) {
        u32x2 pk;
        pk[0] = (unsigned int)f2bf(av[0]) | ((unsigned int)f2bf(av[1]) << 16);
        pk[1] = (unsigned int)f2bf(av[2]) | ((unsigned int)f2bf(av[3]) << 16);
        *(u32x2*)(vtout + (((size_t)(row >> 10) * 16 + (col >> 6)) * 64 + (col & 63)) * 1024
                  + (row & 1023)) = pk;
      } else if (o32) {
        #pragma unroll
        for (int r = 0; r < 4; r++) {
          size_t off = (size_t)(row + r) * N + col;
          float vvv = av[r];
          if (resid) vvv += resid[off];
          o32[off] = vvv;
        }
      } else {
        unsigned short* ob = which == 0 ? ob0 : ob1;
        #pragma unroll
        for (int r = 0; r < 4; r++)
          ob[(size_t)(row + r) * N + col] = f2bf(av[r]);
      }
    }
  }
}

// ---------------- windowed flash attention, 4 waves/block ----------------
__global__ __launch_bounds__(256) void attn4_k(
    const unsigned short* __restrict__ q, const unsigned short* __restrict__ k,
    const unsigned short* __restrict__ vt, unsigned short* __restrict__ att) {
  __shared__ unsigned short Ks[32 * 72];
  __shared__ unsigned short Vt[64 * 40];
  __shared__ unsigned short Ps[4][16 * 40];
  int t0 = blockIdx.x << 6;
  int h = blockIdx.y, b = blockIdx.z;
  int tid = threadIdx.x, lane = tid & 63, w = tid >> 6;
  int lrow = lane & 15, lk8 = (lane >> 4) << 3, fr = (lane >> 4) << 2;
  int qrow = t0 + (w << 4) + lrow;
  size_t qoff = ((size_t)((b << 10) + qrow) << 10) + (h << 6);
  bf16x8 a0 = *(const bf16x8*)(q + qoff + lk8);
  bf16x8 a1 = *(const bf16x8*)(q + qoff + 32 + lk8);
  float m_[4] = {-1e30f, -1e30f, -1e30f, -1e30f};
  float l_[4] = {0.f, 0.f, 0.f, 0.f};
  f32x4 o_[4] = {};
  int s_lo = (511 - ((t0 + 63) >> 1)) & ~31;
  int s_hi = 511 + ((t0 + 64) >> 1);
  int s_end = (s_hi + 32) & ~31;
  int krow = tid >> 3, ks0 = (tid & 7) << 3;
  int vd = tid >> 2, vs0 = (tid & 3) << 3;
  size_t vbase = ((size_t)((b << 4) + h) << 16) + ((size_t)vd << 10);
  unsigned short* Psw = &Ps[w][0];
  for (int s0 = s_lo; s0 < s_end; s0 += 32) {
    u32x4 kv = *(const u32x4*)(k + (((size_t)((b << 10) + s0 + krow)) << 10) + (h << 6) + ks0);
    u32x4 vv = *(const u32x4*)(vt + vbase + s0 + vs0);
    *(u32x4*)(Ks + krow * 72 + ks0) = kv;
    *(u32x4*)(Vt + vd * 40 + vs0) = vv;
    __syncthreads();
    f32x4 sc0 = {}, sc1 = {};
    {
      bf16x8 kb0 = *(const bf16x8*)(Ks + lrow * 72 + lk8);
      bf16x8 kb1 = *(const bf16x8*)(Ks + lrow * 72 + 32 + lk8);
      sc0 = __builtin_amdgcn_mfma_f32_16x16x32_bf16(a0, kb0, sc0, 0, 0, 0);
      sc0 = __builtin_amdgcn_mfma_f32_16x16x32_bf16(a1, kb1, sc0, 0, 0, 0);
      bf16x8 kb2 = *(const bf16x8*)(Ks + (16 + lrow) * 72 + lk8);
      bf16x8 kb3 = *(const bf16x8*)(Ks + (16 + lrow) * 72 + 32 + lk8);
      sc1 = __builtin_amdgcn_mfma_f32_16x16x32_bf16(a0, kb2, sc1, 0, 0, 0);
      sc1 = __builtin_amdgcn_mfma_f32_16x16x32_bf16(a1, kb3, sc1, 0, 0, 0);
    }
    #pragma unroll
    for (int r = 0; r < 4; r++) {
      int t = t0 + (w << 4) + fr + r;
      int lov = 511 - (t >> 1), hiv = 511 + ((t + 1) >> 1);
      int sA = s0 + lrow, sB = sA + 16;
      bool vA = (sA >= lov) && (sA <= hiv);
      bool vB = (sB >= lov) && (sB <= hiv);
      float xA = vA ? sc0[r] * 0.125f : -1e30f;
      float xB = vB ? sc1[r] * 0.125f : -1e30f;
      float tm = fmaxf(xA, xB);
      #pragma unroll
      for (int off = 8; off; off >>= 1) tm = fmaxf(tm, __shfl_xor(tm, off));
      float nm = fmaxf(m_[r], tm);
      float pA = vA ? __expf(xA - nm) : 0.f;
      float pB = vB ? __expf(xB - nm) : 0.f;
      float sca = __expf(m_[r] - nm);
      m_[r] = nm;
      float ps = pA + pB;
      #pragma unroll
      for (int off = 8; off; off >>= 1) ps += __shfl_xor(ps, off);
      l_[r] = l_[r] * sca + ps;
      #pragma unroll
      for (int nb = 0; nb < 4; nb++) o_[nb][r] *= sca;
      Psw[(fr + r) * 40 + lrow]      = f2bf(pA);
      Psw[(fr + r) * 40 + 16 + lrow] = f2bf(pB);
    }
    bf16x8 pa = *(const bf16x8*)(Psw + lrow * 40 + lk8);
    #pragma unroll
    for (int nb = 0; nb < 4; nb++) {
      bf16x8 vb_ = *(const bf16x8*)(Vt + ((nb << 4) + lrow) * 40 + lk8);
      o_[nb] = __builtin_amdgcn_mfma_f32_16x16x32_bf16(pa, vb_, o_[nb], 0, 0, 0);
    }
    __syncthreads();
  }
  #pragma unroll
  for (int nb = 0; nb < 4; nb++)
    #pragma unroll
    for (int r = 0; r < 4; r++) {
      float ov = o_[nb][r] / l_[r];
      att[((size_t)((b << 10) + t0 + (w << 4) + fr + r) << 10) + (h << 6) + (nb << 4) + lrow]
          = f2bf(ov);
    }
}

extern "C" void kernel_launch(void* const* d_in, const int* in_sizes, int n_in,
                              void* d_out, int out_size, void* d_ws, size_t ws_size,
                              hipStream_t stream) {
  (void)in_sizes; (void)n_in; (void)out_size;
  const int*   idx  = (const int*)d_in[0];
  const float* tok  = (const float*)d_in[1];
  const float* pos  = (const float*)d_in[2];
  const float* ln1g = (const float*)d_in[3];
  const float* ln1b = (const float*)d_in[4];
  const float* wq   = (const float*)d_in[5];
  const float* wk   = (const float*)d_in[6];
  const float* wv   = (const float*)d_in[7];
  const float* wpj  = (const float*)d_in[8];
  const float* bpj  = (const float*)d_in[9];
  const float* ln2g = (const float*)d_in[10];
  const float* ln2b = (const float*)d_in[11];
  const float* w1   = (const float*)d_in[12];
  const float* b1   = (const float*)d_in[13];
  const float* w2   = (const float*)d_in[14];
  const float* b2   = (const float*)d_in[15];
  const float* lnfg = (const float*)d_in[16];
  const float* lnfb = (const float*)d_in[17];
  const float* wlm  = (const float*)d_in[18];
  const float* blm  = (const float*)d_in[19];
  float* out = (float*)d_out;

  char* ws = (char*)d_ws;
  const size_t MB = 1u << 20;
  float*          x    = (float*)ws;
  unsigned short* hb   = (unsigned short*)(ws + 8 * MB);
  unsigned short* qb   = (unsigned short*)(ws + 12 * MB);
  unsigned short* kb   = (unsigned short*)(ws + 16 * MB);
  unsigned short* vbuf = (unsigned short*)(ws + 20 * MB);
  unsigned short* ab   = (unsigned short*)(ws + 24 * MB);
  unsigned short* m1   = (unsigned short*)(ws + 28 * MB);
  const int M = 2048, D = 1024;

  embed_k<<<dim3(2048), dim3(256), 0, stream>>>(idx, tok, pos, x);

  unsigned short* wqT  = (unsigned short*)(ws + 44 * MB);
  unsigned short* wkT  = (unsigned short*)(ws + 60 * MB);
  unsigned short* wvT  = (unsigned short*)(ws + 76 * MB);
  unsigned short* wpT  = (unsigned short*)(ws + 92 * MB);
  unsigned short* w1T  = (unsigned short*)(ws + 108 * MB);
  unsigned short* w2T  = (unsigned short*)(ws + 172 * MB);
  unsigned short* wlmT = (unsigned short*)(ws + 236 * MB);
  transp_k<<<dim3(16, 16, 8), 256, 0, stream>>>(wq,   wqT,  1024, 1024);
  transp_k<<<dim3(16, 16, 8), 256, 0, stream>>>(wk,   wkT,  1024, 1024);
  transp_k<<<dim3(16, 16, 8), 256, 0, stream>>>(wv,   wvT,  1024, 1024);
  transp_k<<<dim3(16, 16, 8), 256, 0, stream>>>(wpj,  wpT,  1024, 1024);
  transp_k<<<dim3(64, 16, 8), 256, 0, stream>>>(w1,   w1T,  1024, 4096);
  transp_k<<<dim3(16, 64, 8), 256, 0, stream>>>(w2,   w2T,  4096, 1024);
  transp_k<<<dim3(1000, 16, 1), 256, 0, stream>>>(wlm, wlmT, 1024, 64000);
  for (int l = 0; l < 8; l++) {
    size_t wo = (size_t)l << 20;
    ln_k<<<2048, 256, 0, stream>>>(x, ln1g + l*D, ln1b + l*D, hb);
    gemm_bt<<<dim3(24, 16), 256, 0, stream>>>(hb, wqT + wo, wkT + wo, wvT + wo,
        nullptr, nullptr, qb, kb, vbuf, nullptr, M, D, D, 0);
    attn4_k<<<dim3(16, 16, 2), 256, 0, stream>>>(qb, kb, vbuf, ab);
    gemm_bt<<<dim3(8, 16), 256, 0, stream>>>(ab, wpT + wo, nullptr, nullptr,
        bpj + l*D, x, nullptr, nullptr, nullptr, x, M, D, D, 0);
    ln_k<<<2048, 256, 0, stream>>>(x, ln2g + l*D, ln2b + l*D, hb);
    gemm_bt<<<dim3(32, 16), 256, 0, stream>>>(hb, w1T + ((size_t)l << 22), nullptr, nullptr,
        b1 + (size_t)l*4*D, nullptr, m1, nullptr, nullptr, nullptr, M, 4*D, D, 1);
    gemm_bt<<<dim3(8, 16), 256, 0, stream>>>(m1, w2T + ((size_t)l << 22), nullptr, nullptr,
        b2 + l*D, x, nullptr, nullptr, nullptr, x, M, D, 4*D, 0);
  }
  ln_k<<<2048, 256, 0, stream>>>(x, lnfg, lnfb, hb);
  gemm256_k<<<dim3(2000), 512, 0, stream>>>(hb, wlmT,
      blm, out, nullptr, M, 64000, D, 0);
}

// Round 7
// 2284.578 us; speedup vs baseline: 1.9295x; 1.2595x over previous
//
#include <hip/hip_runtime.h>

typedef __attribute__((ext_vector_type(8))) __bf16 bf16x8;
typedef __attribute__((ext_vector_type(4))) float f32x4;
typedef __attribute__((ext_vector_type(4))) unsigned int u32x4;
typedef __attribute__((ext_vector_type(2))) unsigned int u32x2;

__device__ __forceinline__ unsigned short f2bf(float f) {
  unsigned int u = __float_as_uint(f);
  u += 0x7fffu + ((u >> 16) & 1u);   // RNE
  return (unsigned short)(u >> 16);
}

__device__ __forceinline__ void gload16(const void* g, void* l) {
  __builtin_amdgcn_global_load_lds(
      (const __attribute__((address_space(1))) unsigned int*)g,
      (__attribute__((address_space(3))) unsigned int*)l, 16, 0, 0);
}

// ---------------- embedding ----------------
__global__ __launch_bounds__(256) void embed_k(const int* __restrict__ idx,
    const float* __restrict__ tok, const float* __restrict__ pos,
    float* __restrict__ x) {
  int row = blockIdx.x;
  int t = row & 1023;
  int c = threadIdx.x << 2;
  int id = idx[row];
  f32x4 a = *(const f32x4*)(tok + ((size_t)id << 10) + c);
  f32x4 p = *(const f32x4*)(pos + ((size_t)t << 10) + c);
  a += p;
  *(f32x4*)(x + ((size_t)row << 10) + c) = a;
}

// ---------------- layernorm (f32 in, bf16 out) ----------------
__global__ __launch_bounds__(256) void ln_k(const float* __restrict__ x,
    const float* __restrict__ g, const float* __restrict__ bta,
    unsigned short* __restrict__ out) {
  __shared__ float red[4];
  int row = blockIdx.x, tid = threadIdx.x;
  const float* xr = x + ((size_t)row << 10);
  f32x4 xv = *(const f32x4*)(xr + (tid << 2));
  float s = xv[0] + xv[1] + xv[2] + xv[3];
  #pragma unroll
  for (int off = 32; off; off >>= 1) s += __shfl_xor(s, off);
  if ((tid & 63) == 0) red[tid >> 6] = s;
  __syncthreads();
  float mean = (red[0] + red[1] + red[2] + red[3]) * (1.f / 1024.f);
  __syncthreads();
  f32x4 d = xv - mean;
  float s2 = d[0]*d[0] + d[1]*d[1] + d[2]*d[2] + d[3]*d[3];
  #pragma unroll
  for (int off = 32; off; off >>= 1) s2 += __shfl_xor(s2, off);
  if ((tid & 63) == 0) red[tid >> 6] = s2;
  __syncthreads();
  float var = (red[0] + red[1] + red[2] + red[3]) * (1.f / 1024.f);
  float rs = rsqrtf(var + 1e-5f);
  f32x4 gv = *(const f32x4*)(g + (tid << 2));
  f32x4 bv = *(const f32x4*)(bta + (tid << 2));
  unsigned int p0 = (unsigned int)f2bf(d[0]*rs*gv[0] + bv[0]) |
                    ((unsigned int)f2bf(d[1]*rs*gv[1] + bv[1]) << 16);
  unsigned int p1 = (unsigned int)f2bf(d[2]*rs*gv[2] + bv[2]) |
                    ((unsigned int)f2bf(d[3]*rs*gv[3] + bv[3]) << 16);
  u32x2 o; o[0] = p0; o[1] = p1;
  *(u32x2*)(out + ((size_t)row << 10) + (tid << 2)) = o;
}

// ---------------- weight transpose: f32 [R][C] -> bf16 [C][R] ----------------
__global__ __launch_bounds__(256) void transp_k(const float* __restrict__ in,
    unsigned short* __restrict__ out, int R, int C) {
  __shared__ unsigned short tile[64 * 65];
  size_t lay = (size_t)blockIdx.z * R * C;
  int c0 = blockIdx.x << 6, r0 = blockIdx.y << 6;
  int t = threadIdx.x;
  #pragma unroll
  for (int i = 0; i < 4; i++) {
    int e = (i << 10) + (t << 2);
    int r = e >> 6, c = e & 63;
    f32x4 v = *(const f32x4*)(in + lay + (size_t)(r0 + r) * C + c0 + c);
    tile[r * 65 + c]     = f2bf(v[0]);
    tile[r * 65 + c + 1] = f2bf(v[1]);
    tile[r * 65 + c + 2] = f2bf(v[2]);
    tile[r * 65 + c + 3] = f2bf(v[3]);
  }
  __syncthreads();
  #pragma unroll
  for (int i = 0; i < 4; i++) {
    int e = (i << 10) + (t << 2);
    int cc = e >> 6, rr = e & 63;
    unsigned int a0 = tile[(rr + 0) * 65 + cc];
    unsigned int a1 = tile[(rr + 1) * 65 + cc];
    unsigned int a2 = tile[(rr + 2) * 65 + cc];
    unsigned int a3 = tile[(rr + 3) * 65 + cc];
    u32x2 pk; pk[0] = a0 | (a1 << 16); pk[1] = a2 | (a3 << 16);
    *(u32x2*)(out + lay + (size_t)(c0 + cc) * R + r0 + rr) = pk;
  }
}

// ============ 256x256 8-phase GEMM, frag-reuse quadrant path ============
// Quadrant path per tile: (0,0)->(0,1)->(1,1)->(1,0); each transition shares
// one operand-half held in registers => 28 ds_read_b128/tile (was 48).
// Stages: p1:{buf1.B1,B0<-T+1}(4), p2:buf1.A1(2), p3:buf0.A0<-T+2, p4:buf0.B1,
// p5:buf0.B0, p6:buf0.A1, p7:buf1.A0<-T+3, p8:none.
// vmcnt ledger (verified steady+tail): p4 vmcnt(6|2), p6 vmcnt(8|0), p8 vmcnt(2|-).
// Invariant entering p1: in-flight = {buf1.A0} (2 loads).
// XCD map: bm fast => each XCD owns a bn column-stripe of B (read once).
#define VMC6 asm volatile("s_waitcnt vmcnt(6)" ::: "memory")
#define VMC8 asm volatile("s_waitcnt vmcnt(8)" ::: "memory")
#define VMC2 asm volatile("s_waitcnt vmcnt(2)" ::: "memory")
#define VMC0 asm volatile("s_waitcnt vmcnt(0)" ::: "memory")

__global__ __launch_bounds__(512, 2) void gemm256_k(
    const unsigned short* __restrict__ A, const unsigned short* __restrict__ Bt,
    const float* __restrict__ bias, float* __restrict__ o32,
    unsigned short* __restrict__ obf, int M, int N, int K, int relu) {
  __shared__ unsigned short lds[2][2][2][8192];
  int mb = M >> 8;
  int wg = blockIdx.x, nwg = gridDim.x;
  int cpx = nwg >> 3;
  int swz = (wg & 7) * cpx + (wg >> 3);      // nwg % 8 == 0
  int bm = swz % mb, bn = swz / mb;          // bm fast: per-XCD bn-stripes
  int m0 = bm << 8, n0 = bn << 8;
  int tid = threadIdx.x, lane = tid & 63, wave = tid >> 6;
  int wrow = wave >> 2, wcol = wave & 3;
  int lrow = lane & 15, g4 = lane >> 4, l7 = lane & 7;
  f32x4 acc[8][4] = {};
  bf16x8 af[8], bfv[4];
  const unsigned short* Ag = A + (size_t)m0 * K;
  const unsigned short* Bg = Bt + (size_t)n0 * K;
  auto stage = [&](int op, int b, int h, int kt) {
    const unsigned short* gb = (op ? Bg : Ag) + ((size_t)(h << 7)) * K + kt;
    char* lb = (char*)&lds[op][b][h][0];
    #pragma unroll
    for (int g = 0; g < 2; g++) {
      int row = (g << 6) + (wave << 3) + (lane >> 3);
      int klog = ((lane & 7) ^ ((lane >> 3) & 7)) << 3;   // shorts
      gload16(gb + (size_t)row * K + klog, lb + (g << 13) + (wave << 10));
    }
  };

#define PH(bi, qa, qb, LA, LB, STG, VM)                                        \
  {                                                                            \
    if (LA) {                                                                  \
      const unsigned short* Ah = &lds[0][bi][qa][0];                           \
      _Pragma("unroll")                                                        \
      for (int i = 0; i < 4; i++) {                                            \
        int rl = (wrow << 6) + (i << 4) + lrow;                                \
        af[i*2+0] = *(const bf16x8*)(Ah + rl * 64 + ((g4 ^ l7) << 3));         \
        af[i*2+1] = *(const bf16x8*)(Ah + rl * 64 + (((4 + g4) ^ l7) << 3));   \
      }                                                                        \
    }                                                                          \
    if (LB) {                                                                  \
      const unsigned short* Bh = &lds[1][bi][qb][0];                           \
      _Pragma("unroll")                                                        \
      for (int j = 0; j < 2; j++) {                                            \
        int cl = (wcol << 5) + (j << 4) + lrow;                                \
        bfv[j*2+0] = *(const bf16x8*)(Bh + cl * 64 + ((g4 ^ l7) << 3));        \
        bfv[j*2+1] = *(const bf16x8*)(Bh + cl * 64 + (((4 + g4) ^ l7) << 3));  \
      }                                                                        \
    }                                                                          \
    STG;                                                                       \
    __builtin_amdgcn_s_barrier();                                              \
    asm volatile("s_waitcnt lgkmcnt(0)" ::: "memory");                         \
    __builtin_amdgcn_sched_barrier(0);                                         \
    __builtin_amdgcn_s_setprio(1);                                             \
    _Pragma("unroll")                                                          \
    for (int i = 0; i < 4; i++)                                                \
      _Pragma("unroll")                                                        \
      for (int j = 0; j < 2; j++) {                                            \
        acc[(qa)*4+i][(qb)*2+j] = __builtin_amdgcn_mfma_f32_16x16x32_bf16(     \
            af[i*2+0], bfv[j*2+0], acc[(qa)*4+i][(qb)*2+j], 0, 0, 0);          \
        acc[(qa)*4+i][(qb)*2+j] = __builtin_amdgcn_mfma_f32_16x16x32_bf16(     \
            af[i*2+1], bfv[j*2+1], acc[(qa)*4+i][(qb)*2+j], 0, 0, 0);          \
      }                                                                        \
    __builtin_amdgcn_s_setprio(0);                                             \
    VM;                                                                        \
    __builtin_amdgcn_s_barrier();                                              \
  }

  int nt = K >> 6;          // K-tiles; nt even (K%128==0)
  int nit = nt >> 1;
  // prologue: buf0 <- tile0 (4 halves), buf1.A0 <- tile1. vmcnt(2) leaves
  // exactly {buf1.A0} in flight == loop invariant.
  stage(0, 0, 0, 0); stage(1, 0, 0, 0); stage(1, 0, 1, 0); stage(0, 0, 1, 0);
  stage(0, 1, 0, 64);
  VMC2;
  __builtin_amdgcn_s_barrier();
  for (int it = 0; it < nit; ++it) {
    int kT1 = ((it << 1) + 1) << 6;
    int kT2 = ((it << 1) + 2) << 6;
    int kT3 = ((it << 1) + 3) << 6;
    bool m2 = (it + 1) < nit;
    PH(0, 0, 0, 1, 1, { stage(1, 1, 1, kT1); stage(1, 1, 0, kT1); }, )
    PH(0, 0, 1, 0, 1, { stage(0, 1, 1, kT1); }, )
    PH(0, 1, 1, 1, 0, if (m2) { stage(0, 0, 0, kT2); }, )
    PH(0, 1, 0, 0, 1, if (m2) { stage(1, 0, 1, kT2); },
       if (m2) { VMC6; } else { VMC2; })
    PH(1, 0, 0, 1, 1, if (m2) { stage(1, 0, 0, kT2); }, )
    PH(1, 0, 1, 0, 1, if (m2) { stage(0, 0, 1, kT2); },
       if (m2) { VMC8; } else { VMC0; })
    PH(1, 1, 1, 1, 0, if (m2) { stage(0, 1, 0, kT3); }, )
    PH(1, 1, 0, 0, 1, , if (m2) { VMC2; })
  }
#undef PH
  int frow = g4 << 2;
  #pragma unroll
  for (int rt = 0; rt < 8; rt++) {
    int qa = rt >> 2, i = rt & 3;
    int grow = m0 + (qa << 7) + (wrow << 6) + (i << 4) + frow;
    #pragma unroll
    for (int ct = 0; ct < 4; ct++) {
      int qb = ct >> 1, j = ct & 1;
      int gcol = n0 + (qb << 7) + (wcol << 5) + (j << 4) + lrow;
      float bb = bias ? bias[gcol] : 0.f;
      f32x4 av = acc[rt][ct];
      #pragma unroll
      for (int r = 0; r < 4; r++) {
        float vv = av[r] + bb;
        if (relu) vv = fmaxf(vv, 0.f);
        if (o32) o32[(size_t)(grow + r) * N + gcol] = vv;
        else obf[(size_t)(grow + r) * N + gcol] = f2bf(vv);
      }
    }
  }
}

// ---------------- m97-structure GEMM (layer GEMMs) ----------------
__global__ __launch_bounds__(256) void gemm_bt(
    const unsigned short* __restrict__ A,
    const unsigned short* __restrict__ Bt0, const unsigned short* __restrict__ Bt1,
    const unsigned short* __restrict__ Bt2,
    const float* __restrict__ bias, const float* resid,
    unsigned short* __restrict__ ob0, unsigned short* __restrict__ ob1,
    unsigned short* __restrict__ vtout, float* o32,
    int M, int N, int K, int relu) {
  __shared__ unsigned short As[128 * 64];
  __shared__ unsigned short Bs[128 * 64];
  int nbp = N >> 7;
  int which = blockIdx.x / nbp;
  int bx = blockIdx.x - which * nbp;
  const unsigned short* Bt = which == 0 ? Bt0 : (which == 1 ? Bt1 : Bt2);
  int m0 = blockIdx.y << 7, n0 = bx << 7;
  int tid = threadIdx.x, lane = tid & 63, wave = tid >> 6;
  int wr = (wave >> 1) << 6, wc = (wave & 1) << 6;
  int lrow = lane & 15, lk8 = (lane >> 4) << 3;
  int wbase = wave << 12;
  f32x4 acc[4][4] = {};
  const unsigned short* Ag = A + (size_t)m0 * K;
  const unsigned short* Bg = Bt + (size_t)n0 * K;
  for (int k0 = 0; k0 < K; k0 += 64) {
    #pragma unroll
    for (int i = 0; i < 4; i++) {
      int o = wbase + (i << 10) + (lane << 4);
      int r = o >> 7, c = (o & 127) >> 1;
      gload16(Ag + (size_t)r * K + k0 + c, (char*)As + wbase + (i << 10));
      gload16(Bg + (size_t)r * K + k0 + c, (char*)Bs + wbase + (i << 10));
    }
    __syncthreads();
    #pragma unroll
    for (int ks = 0; ks < 2; ks++) {
      bf16x8 af[4], bfv[4];
      #pragma unroll
      for (int i = 0; i < 4; i++)
        af[i] = *(const bf16x8*)(As + ((wr + (i << 4) + lrow) << 6) + (ks << 5) + lk8);
      #pragma unroll
      for (int i = 0; i < 4; i++)
        bfv[i] = *(const bf16x8*)(Bs + ((wc + (i << 4) + lrow) << 6) + (ks << 5) + lk8);
      #pragma unroll
      for (int mi = 0; mi < 4; mi++)
        #pragma unroll
        for (int ni = 0; ni < 4; ni++)
          acc[mi][ni] = __builtin_amdgcn_mfma_f32_16x16x32_bf16(af[mi], bfv[ni], acc[mi][ni], 0, 0, 0);
    }
    __syncthreads();
  }
  int fr = (lane >> 4) << 2;
  #pragma unroll
  for (int mi = 0; mi < 4; mi++) {
    #pragma unroll
    for (int ni = 0; ni < 4; ni++) {
      int row = m0 + wr + (mi << 4) + fr;
      int col = n0 + wc + (ni << 4) + lrow;
      f32x4 av = acc[mi][ni];
      if (bias) {
        float bb = bias[col];
        av[0] += bb; av[1] += bb; av[2] += bb; av[3] += bb;
      }
      if (relu) {
        av[0] = fmaxf(av[0], 0.f); av[1] = fmaxf(av[1], 0.f);
        av[2] = fmaxf(av[2], 0.f); av[3] = fmaxf(av[3], 0.f);
      }
      if (which == 2) {
        u32x2 pk;
        pk[0] = (unsigned int)f2bf(av[0]) | ((unsigned int)f2bf(av[1]) << 16);
        pk[1] = (unsigned int)f2bf(av[2]) | ((unsigned int)f2bf(av[3]) << 16);
        *(u32x2*)(vtout + (((size_t)(row >> 10) * 16 + (col >> 6)) * 64 + (col & 63)) * 1024
                  + (row & 1023)) = pk;
      } else if (o32) {
        #pragma unroll
        for (int r = 0; r < 4; r++) {
          size_t off = (size_t)(row + r) * N + col;
          float vvv = av[r];
          if (resid) vvv += resid[off];
          o32[off] = vvv;
        }
      } else {
        unsigned short* ob = which == 0 ? ob0 : ob1;
        #pragma unroll
        for (int r = 0; r < 4; r++)
          ob[(size_t)(row + r) * N + col] = f2bf(av[r]);
      }
    }
  }
}

// ---------------- split-K GEMM: partial f32, no epilogue ----------------
__global__ __launch_bounds__(256) void gemm_splitk(
    const unsigned short* __restrict__ A, const unsigned short* __restrict__ Bt,
    float* __restrict__ pbuf, int M, int N, int K, int KS) {
  __shared__ unsigned short As[128 * 64];
  __shared__ unsigned short Bs[128 * 64];
  int m0 = blockIdx.y << 7, n0 = blockIdx.x << 7;
  int kz = blockIdx.z * KS;
  int tid = threadIdx.x, lane = tid & 63, wave = tid >> 6;
  int wr = (wave >> 1) << 6, wc = (wave & 1) << 6;
  int lrow = lane & 15, lk8 = (lane >> 4) << 3;
  int wbase = wave << 12;
  f32x4 acc[4][4] = {};
  const unsigned short* Ag = A + (size_t)m0 * K;
  const unsigned short* Bg = Bt + (size_t)n0 * K;
  for (int k0 = kz; k0 < kz + KS; k0 += 64) {
    #pragma unroll
    for (int i = 0; i < 4; i++) {
      int o = wbase + (i << 10) + (lane << 4);
      int r = o >> 7, c = (o & 127) >> 1;
      gload16(Ag + (size_t)r * K + k0 + c, (char*)As + wbase + (i << 10));
      gload16(Bg + (size_t)r * K + k0 + c, (char*)Bs + wbase + (i << 10));
    }
    __syncthreads();
    #pragma unroll
    for (int ks = 0; ks < 2; ks++) {
      bf16x8 af[4], bfv[4];
      #pragma unroll
      for (int i = 0; i < 4; i++)
        af[i] = *(const bf16x8*)(As + ((wr + (i << 4) + lrow) << 6) + (ks << 5) + lk8);
      #pragma unroll
      for (int i = 0; i < 4; i++)
        bfv[i] = *(const bf16x8*)(Bs + ((wc + (i << 4) + lrow) << 6) + (ks << 5) + lk8);
      #pragma unroll
      for (int mi = 0; mi < 4; mi++)
        #pragma unroll
        for (int ni = 0; ni < 4; ni++)
          acc[mi][ni] = __builtin_amdgcn_mfma_f32_16x16x32_bf16(af[mi], bfv[ni], acc[mi][ni], 0, 0, 0);
    }
    __syncthreads();
  }
  int fr = (lane >> 4) << 2;
  float* pb = pbuf + (size_t)blockIdx.z * M * N;
  #pragma unroll
  for (int mi = 0; mi < 4; mi++)
    #pragma unroll
    for (int ni = 0; ni < 4; ni++) {
      int row = m0 + wr + (mi << 4) + fr;
      int col = n0 + wc + (ni << 4) + lrow;
      #pragma unroll
      for (int r = 0; r < 4; r++)
        pb[(size_t)(row + r) * N + col] = acc[mi][ni][r];
    }
}

// x[row][c] += bias[c] + sum_z pbuf[z][row][c]   (M=2048, N=1024)
__global__ __launch_bounds__(256) void reduce_k(float* __restrict__ x,
    const float* __restrict__ pbuf, const float* __restrict__ bias, int nz) {
  int row = blockIdx.x, c = threadIdx.x << 2;
  size_t off = ((size_t)row << 10) + c;
  f32x4 s = *(const f32x4*)(bias + c);
  for (int z = 0; z < nz; z++)
    s += *(const f32x4*)(pbuf + ((size_t)z << 21) + off);
  f32x4 xv = *(const f32x4*)(x + off);
  xv += s;
  *(f32x4*)(x + off) = xv;
}

// ---------------- windowed flash attention, 4 waves/block ----------------
__global__ __launch_bounds__(256) void attn4_k(
    const unsigned short* __restrict__ q, const unsigned short* __restrict__ k,
    const unsigned short* __restrict__ vt, unsigned short* __restrict__ att) {
  __shared__ unsigned short Ks[32 * 72];
  __shared__ unsigned short Vt[64 * 40];
  __shared__ unsigned short Ps[4][16 * 40];
  int t0 = blockIdx.x << 6;
  int h = blockIdx.y, b = blockIdx.z;
  int tid = threadIdx.x, lane = tid & 63, w = tid >> 6;
  int lrow = lane & 15, lk8 = (lane >> 4) << 3, fr = (lane >> 4) << 2;
  int qrow = t0 + (w << 4) + lrow;
  size_t qoff = ((size_t)((b << 10) + qrow) << 10) + (h << 6);
  bf16x8 a0 = *(const bf16x8*)(q + qoff + lk8);
  bf16x8 a1 = *(const bf16x8*)(q + qoff + 32 + lk8);
  float m_[4] = {-1e30f, -1e30f, -1e30f, -1e30f};
  float l_[4] = {0.f, 0.f, 0.f, 0.f};
  f32x4 o_[4] = {};
  int s_lo = (511 - ((t0 + 63) >> 1)) & ~31;
  int s_hi = 511 + ((t0 + 64) >> 1);
  int s_end = (s_hi + 32) & ~31;
  int krow = tid >> 3, ks0 = (tid & 7) << 3;
  int vd = tid >> 2, vs0 = (tid & 3) << 3;
  size_t vbase = ((size_t)((b << 4) + h) << 16) + ((size_t)vd << 10);
  unsigned short* Psw = &Ps[w][0];
  for (int s0 = s_lo; s0 < s_end; s0 += 32) {
    u32x4 kv = *(const u32x4*)(k + (((size_t)((b << 10) + s0 + krow)) << 10) + (h << 6) + ks0);
    u32x4 vv = *(const u32x4*)(vt + vbase + s0 + vs0);
    *(u32x4*)(Ks + krow * 72 + ks0) = kv;
    *(u32x4*)(Vt + vd * 40 + vs0) = vv;
    __syncthreads();
    f32x4 sc0 = {}, sc1 = {};
    {
      bf16x8 kb0 = *(const bf16x8*)(Ks + lrow * 72 + lk8);
      bf16x8 kb1 = *(const bf16x8*)(Ks + lrow * 72 + 32 + lk8);
      sc0 = __builtin_amdgcn_mfma_f32_16x16x32_bf16(a0, kb0, sc0, 0, 0, 0);
      sc0 = __builtin_amdgcn_mfma_f32_16x16x32_bf16(a1, kb1, sc0, 0, 0, 0);
      bf16x8 kb2 = *(const bf16x8*)(Ks + (16 + lrow) * 72 + lk8);
      bf16x8 kb3 = *(const bf16x8*)(Ks + (16 + lrow) * 72 + 32 + lk8);
      sc1 = __builtin_amdgcn_mfma_f32_16x16x32_bf16(a0, kb2, sc1, 0, 0, 0);
      sc1 = __builtin_amdgcn_mfma_f32_16x16x32_bf16(a1, kb3, sc1, 0, 0, 0);
    }
    #pragma unroll
    for (int r = 0; r < 4; r++) {
      int t = t0 + (w << 4) + fr + r;
      int lov = 511 - (t >> 1), hiv = 511 + ((t + 1) >> 1);
      int sA = s0 + lrow, sB = sA + 16;
      bool vA = (sA >= lov) && (sA <= hiv);
      bool vB = (sB >= lov) && (sB <= hiv);
      float xA = vA ? sc0[r] * 0.125f : -1e30f;
      float xB = vB ? sc1[r] * 0.125f : -1e30f;
      float tm = fmaxf(xA, xB);
      #pragma unroll
      for (int off = 8; off; off >>= 1) tm = fmaxf(tm, __shfl_xor(tm, off));
      float nm = fmaxf(m_[r], tm);
      float pA = vA ? __expf(xA - nm) : 0.f;
      float pB = vB ? __expf(xB - nm) : 0.f;
      float sca = __expf(m_[r] - nm);
      m_[r] = nm;
      float ps = pA + pB;
      #pragma unroll
      for (int off = 8; off; off >>= 1) ps += __shfl_xor(ps, off);
      l_[r] = l_[r] * sca + ps;
      #pragma unroll
      for (int nb = 0; nb < 4; nb++) o_[nb][r] *= sca;
      Psw[(fr + r) * 40 + lrow]      = f2bf(pA);
      Psw[(fr + r) * 40 + 16 + lrow] = f2bf(pB);
    }
    bf16x8 pa = *(const bf16x8*)(Psw + lrow * 40 + lk8);
    #pragma unroll
    for (int nb = 0; nb < 4; nb++) {
      bf16x8 vb_ = *(const bf16x8*)(Vt + ((nb << 4) + lrow) * 40 + lk8);
      o_[nb] = __builtin_amdgcn_mfma_f32_16x16x32_bf16(pa, vb_, o_[nb], 0, 0, 0);
    }
    __syncthreads();
  }
  #pragma unroll
  for (int nb = 0; nb < 4; nb++)
    #pragma unroll
    for (int r = 0; r < 4; r++) {
      float ov = o_[nb][r] / l_[r];
      att[((size_t)((b << 10) + t0 + (w << 4) + fr + r) << 10) + (h << 6) + (nb << 4) + lrow]
          = f2bf(ov);
    }
}

extern "C" void kernel_launch(void* const* d_in, const int* in_sizes, int n_in,
                              void* d_out, int out_size, void* d_ws, size_t ws_size,
                              hipStream_t stream) {
  (void)in_sizes; (void)n_in; (void)out_size;
  const int*   idx  = (const int*)d_in[0];
  const float* tok  = (const float*)d_in[1];
  const float* pos  = (const float*)d_in[2];
  const float* ln1g = (const float*)d_in[3];
  const float* ln1b = (const float*)d_in[4];
  const float* wq   = (const float*)d_in[5];
  const float* wk   = (const float*)d_in[6];
  const float* wv   = (const float*)d_in[7];
  const float* wpj  = (const float*)d_in[8];
  const float* bpj  = (const float*)d_in[9];
  const float* ln2g = (const float*)d_in[10];
  const float* ln2b = (const float*)d_in[11];
  const float* w1   = (const float*)d_in[12];
  const float* b1   = (const float*)d_in[13];
  const float* w2   = (const float*)d_in[14];
  const float* b2   = (const float*)d_in[15];
  const float* lnfg = (const float*)d_in[16];
  const float* lnfb = (const float*)d_in[17];
  const float* wlm  = (const float*)d_in[18];
  const float* blm  = (const float*)d_in[19];
  float* out = (float*)d_out;

  char* ws = (char*)d_ws;
  const size_t MB = 1u << 20;
  float*          x    = (float*)ws;
  unsigned short* hb   = (unsigned short*)(ws + 8 * MB);
  unsigned short* qb   = (unsigned short*)(ws + 12 * MB);
  unsigned short* kb   = (unsigned short*)(ws + 16 * MB);
  unsigned short* vbuf = (unsigned short*)(ws + 20 * MB);
  unsigned short* ab   = (unsigned short*)(ws + 24 * MB);
  unsigned short* m1   = (unsigned short*)(ws + 28 * MB);
  const int M = 2048, D = 1024;

  // split-K scratch: prefer 4-way at 376MB (past wlmT end 367MB); else 2-way
  // overlapping hb/qb/kb/vbuf (dead at mlp2 time).
  int nz; float* pb;
  if (ws_size >= 408 * MB) { nz = 4; pb = (float*)(ws + 376 * MB); }
  else                     { nz = 2; pb = (float*)(ws + 8 * MB); }

  embed_k<<<dim3(2048), dim3(256), 0, stream>>>(idx, tok, pos, x);

  unsigned short* wqT  = (unsigned short*)(ws + 44 * MB);
  unsigned short* wkT  = (unsigned short*)(ws + 60 * MB);
  unsigned short* wvT  = (unsigned short*)(ws + 76 * MB);
  unsigned short* wpT  = (unsigned short*)(ws + 92 * MB);
  unsigned short* w1T  = (unsigned short*)(ws + 108 * MB);
  unsigned short* w2T  = (unsigned short*)(ws + 172 * MB);
  unsigned short* wlmT = (unsigned short*)(ws + 236 * MB);
  transp_k<<<dim3(16, 16, 8), 256, 0, stream>>>(wq,   wqT,  1024, 1024);
  transp_k<<<dim3(16, 16, 8), 256, 0, stream>>>(wk,   wkT,  1024, 1024);
  transp_k<<<dim3(16, 16, 8), 256, 0, stream>>>(wv,   wvT,  1024, 1024);
  transp_k<<<dim3(16, 16, 8), 256, 0, stream>>>(wpj,  wpT,  1024, 1024);
  transp_k<<<dim3(64, 16, 8), 256, 0, stream>>>(w1,   w1T,  1024, 4096);
  transp_k<<<dim3(16, 64, 8), 256, 0, stream>>>(w2,   w2T,  4096, 1024);
  transp_k<<<dim3(1000, 16, 1), 256, 0, stream>>>(wlm, wlmT, 1024, 64000);
  for (int l = 0; l < 8; l++) {
    size_t wo = (size_t)l << 20;
    ln_k<<<2048, 256, 0, stream>>>(x, ln1g + l*D, ln1b + l*D, hb);
    gemm_bt<<<dim3(24, 16), 256, 0, stream>>>(hb, wqT + wo, wkT + wo, wvT + wo,
        nullptr, nullptr, qb, kb, vbuf, nullptr, M, D, D, 0);
    attn4_k<<<dim3(16, 16, 2), 256, 0, stream>>>(qb, kb, vbuf, ab);
    gemm_bt<<<dim3(8, 16), 256, 0, stream>>>(ab, wpT + wo, nullptr, nullptr,
        bpj + l*D, x, nullptr, nullptr, nullptr, x, M, D, D, 0);
    ln_k<<<2048, 256, 0, stream>>>(x, ln2g + l*D, ln2b + l*D, hb);
    gemm_bt<<<dim3(32, 16), 256, 0, stream>>>(hb, w1T + ((size_t)l << 22), nullptr, nullptr,
        b1 + (size_t)l*4*D, nullptr, m1, nullptr, nullptr, nullptr, M, 4*D, D, 1);
    gemm_splitk<<<dim3(8, 16, nz), 256, 0, stream>>>(m1, w2T + ((size_t)l << 22),
        pb, M, D, 4*D, 4*D / nz);
    reduce_k<<<2048, 256, 0, stream>>>(x, pb, b2 + l*D, nz);
  }
  ln_k<<<2048, 256, 0, stream>>>(x, lnfg, lnfb, hb);
  gemm256_k<<<dim3(2000), 512, 0, stream>>>(hb, wlmT,
      blm, out, nullptr, M, 64000, D, 0);
}

// Round 8
// 2175.177 us; speedup vs baseline: 2.0266x; 1.0503x over previous
//
#include <hip/hip_runtime.h>

typedef __attribute__((ext_vector_type(8))) __bf16 bf16x8;
typedef __attribute__((ext_vector_type(4))) float f32x4;
typedef __attribute__((ext_vector_type(4))) unsigned int u32x4;
typedef __attribute__((ext_vector_type(2))) unsigned int u32x2;

__device__ __forceinline__ unsigned short f2bf(float f) {
  unsigned int u = __float_as_uint(f);
  u += 0x7fffu + ((u >> 16) & 1u);   // RNE
  return (unsigned short)(u >> 16);
}

__device__ __forceinline__ void gload16(const void* g, void* l) {
  __builtin_amdgcn_global_load_lds(
      (const __attribute__((address_space(1))) unsigned int*)g,
      (__attribute__((address_space(3))) unsigned int*)l, 16, 0, 0);
}

// ---------------- embedding ----------------
__global__ __launch_bounds__(256) void embed_k(const int* __restrict__ idx,
    const float* __restrict__ tok, const float* __restrict__ pos,
    float* __restrict__ x) {
  int row = blockIdx.x;
  int t = row & 1023;
  int c = threadIdx.x << 2;
  int id = idx[row];
  f32x4 a = *(const f32x4*)(tok + ((size_t)id << 10) + c);
  f32x4 p = *(const f32x4*)(pos + ((size_t)t << 10) + c);
  a += p;
  *(f32x4*)(x + ((size_t)row << 10) + c) = a;
}

// ---------------- layernorm (f32 in, bf16 out) ----------------
__global__ __launch_bounds__(256) void ln_k(const float* __restrict__ x,
    const float* __restrict__ g, const float* __restrict__ bta,
    unsigned short* __restrict__ out) {
  __shared__ float red[4];
  int row = blockIdx.x, tid = threadIdx.x;
  const float* xr = x + ((size_t)row << 10);
  f32x4 xv = *(const f32x4*)(xr + (tid << 2));
  float s = xv[0] + xv[1] + xv[2] + xv[3];
  #pragma unroll
  for (int off = 32; off; off >>= 1) s += __shfl_xor(s, off);
  if ((tid & 63) == 0) red[tid >> 6] = s;
  __syncthreads();
  float mean = (red[0] + red[1] + red[2] + red[3]) * (1.f / 1024.f);
  __syncthreads();
  f32x4 d = xv - mean;
  float s2 = d[0]*d[0] + d[1]*d[1] + d[2]*d[2] + d[3]*d[3];
  #pragma unroll
  for (int off = 32; off; off >>= 1) s2 += __shfl_xor(s2, off);
  if ((tid & 63) == 0) red[tid >> 6] = s2;
  __syncthreads();
  float var = (red[0] + red[1] + red[2] + red[3]) * (1.f / 1024.f);
  float rs = rsqrtf(var + 1e-5f);
  f32x4 gv = *(const f32x4*)(g + (tid << 2));
  f32x4 bv = *(const f32x4*)(bta + (tid << 2));
  unsigned int p0 = (unsigned int)f2bf(d[0]*rs*gv[0] + bv[0]) |
                    ((unsigned int)f2bf(d[1]*rs*gv[1] + bv[1]) << 16);
  unsigned int p1 = (unsigned int)f2bf(d[2]*rs*gv[2] + bv[2]) |
                    ((unsigned int)f2bf(d[3]*rs*gv[3] + bv[3]) << 16);
  u32x2 o; o[0] = p0; o[1] = p1;
  *(u32x2*)(out + ((size_t)row << 10) + (tid << 2)) = o;
}

// ---------------- weight transpose: f32 [R][C] -> bf16 [C][R] ----------------
__global__ __launch_bounds__(256) void transp_k(const float* __restrict__ in,
    unsigned short* __restrict__ out, int R, int C) {
  __shared__ unsigned short tile[64 * 65];
  size_t lay = (size_t)blockIdx.z * R * C;
  int c0 = blockIdx.x << 6, r0 = blockIdx.y << 6;
  int t = threadIdx.x;
  #pragma unroll
  for (int i = 0; i < 4; i++) {
    int e = (i << 10) + (t << 2);
    int r = e >> 6, c = e & 63;
    f32x4 v = *(const f32x4*)(in + lay + (size_t)(r0 + r) * C + c0 + c);
    tile[r * 65 + c]     = f2bf(v[0]);
    tile[r * 65 + c + 1] = f2bf(v[1]);
    tile[r * 65 + c + 2] = f2bf(v[2]);
    tile[r * 65 + c + 3] = f2bf(v[3]);
  }
  __syncthreads();
  #pragma unroll
  for (int i = 0; i < 4; i++) {
    int e = (i << 10) + (t << 2);
    int cc = e >> 6, rr = e & 63;
    unsigned int a0 = tile[(rr + 0) * 65 + cc];
    unsigned int a1 = tile[(rr + 1) * 65 + cc];
    unsigned int a2 = tile[(rr + 2) * 65 + cc];
    unsigned int a3 = tile[(rr + 3) * 65 + cc];
    u32x2 pk; pk[0] = a0 | (a1 << 16); pk[1] = a2 | (a3 << 16);
    *(u32x2*)(out + lay + (size_t)(c0 + cc) * R + r0 + rr) = pk;
  }
}

// ============ 256x256 8-phase GEMM, frag-reuse quadrant path ============
#define VMC6 asm volatile("s_waitcnt vmcnt(6)" ::: "memory")
#define VMC8 asm volatile("s_waitcnt vmcnt(8)" ::: "memory")
#define VMC2 asm volatile("s_waitcnt vmcnt(2)" ::: "memory")
#define VMC0 asm volatile("s_waitcnt vmcnt(0)" ::: "memory")

__global__ __launch_bounds__(512, 2) void gemm256_k(
    const unsigned short* __restrict__ A, const unsigned short* __restrict__ Bt,
    const float* __restrict__ bias, float* __restrict__ o32,
    unsigned short* __restrict__ obf, int M, int N, int K, int relu) {
  __shared__ unsigned short lds[2][2][2][8192];
  int mb = M >> 8;
  int wg = blockIdx.x, nwg = gridDim.x;
  int cpx = nwg >> 3;
  int swz = (wg & 7) * cpx + (wg >> 3);      // nwg % 8 == 0
  int bm = swz % mb, bn = swz / mb;          // bm fast: per-XCD bn-stripes
  int m0 = bm << 8, n0 = bn << 8;
  int tid = threadIdx.x, lane = tid & 63, wave = tid >> 6;
  int wrow = wave >> 2, wcol = wave & 3;
  int lrow = lane & 15, g4 = lane >> 4, l7 = lane & 7;
  f32x4 acc[8][4] = {};
  bf16x8 af[8], bfv[4];
  const unsigned short* Ag = A + (size_t)m0 * K;
  const unsigned short* Bg = Bt + (size_t)n0 * K;
  auto stage = [&](int op, int b, int h, int kt) {
    const unsigned short* gb = (op ? Bg : Ag) + ((size_t)(h << 7)) * K + kt;
    char* lb = (char*)&lds[op][b][h][0];
    #pragma unroll
    for (int g = 0; g < 2; g++) {
      int row = (g << 6) + (wave << 3) + (lane >> 3);
      int klog = ((lane & 7) ^ ((lane >> 3) & 7)) << 3;   // shorts
      gload16(gb + (size_t)row * K + klog, lb + (g << 13) + (wave << 10));
    }
  };

#define PH(bi, qa, qb, LA, LB, STG, VM)                                        \
  {                                                                            \
    if (LA) {                                                                  \
      const unsigned short* Ah = &lds[0][bi][qa][0];                           \
      _Pragma("unroll")                                                        \
      for (int i = 0; i < 4; i++) {                                            \
        int rl = (wrow << 6) + (i << 4) + lrow;                                \
        af[i*2+0] = *(const bf16x8*)(Ah + rl * 64 + ((g4 ^ l7) << 3));         \
        af[i*2+1] = *(const bf16x8*)(Ah + rl * 64 + (((4 + g4) ^ l7) << 3));   \
      }                                                                        \
    }                                                                          \
    if (LB) {                                                                  \
      const unsigned short* Bh = &lds[1][bi][qb][0];                           \
      _Pragma("unroll")                                                        \
      for (int j = 0; j < 2; j++) {                                            \
        int cl = (wcol << 5) + (j << 4) + lrow;                                \
        bfv[j*2+0] = *(const bf16x8*)(Bh + cl * 64 + ((g4 ^ l7) << 3));        \
        bfv[j*2+1] = *(const bf16x8*)(Bh + cl * 64 + (((4 + g4) ^ l7) << 3));  \
      }                                                                        \
    }                                                                          \
    STG;                                                                       \
    __builtin_amdgcn_s_barrier();                                              \
    asm volatile("s_waitcnt lgkmcnt(0)" ::: "memory");                         \
    __builtin_amdgcn_sched_barrier(0);                                         \
    __builtin_amdgcn_s_setprio(1);                                             \
    _Pragma("unroll")                                                          \
    for (int i = 0; i < 4; i++)                                                \
      _Pragma("unroll")                                                        \
      for (int j = 0; j < 2; j++) {                                            \
        acc[(qa)*4+i][(qb)*2+j] = __builtin_amdgcn_mfma_f32_16x16x32_bf16(     \
            af[i*2+0], bfv[j*2+0], acc[(qa)*4+i][(qb)*2+j], 0, 0, 0);          \
        acc[(qa)*4+i][(qb)*2+j] = __builtin_amdgcn_mfma_f32_16x16x32_bf16(     \
            af[i*2+1], bfv[j*2+1], acc[(qa)*4+i][(qb)*2+j], 0, 0, 0);          \
      }                                                                        \
    __builtin_amdgcn_s_setprio(0);                                             \
    VM;                                                                        \
    __builtin_amdgcn_s_barrier();                                              \
  }

  int nt = K >> 6;          // K-tiles; nt even (K%128==0)
  int nit = nt >> 1;
  stage(0, 0, 0, 0); stage(1, 0, 0, 0); stage(1, 0, 1, 0); stage(0, 0, 1, 0);
  stage(0, 1, 0, 64);
  VMC2;
  __builtin_amdgcn_s_barrier();
  for (int it = 0; it < nit; ++it) {
    int kT1 = ((it << 1) + 1) << 6;
    int kT2 = ((it << 1) + 2) << 6;
    int kT3 = ((it << 1) + 3) << 6;
    bool m2 = (it + 1) < nit;
    PH(0, 0, 0, 1, 1, { stage(1, 1, 1, kT1); stage(1, 1, 0, kT1); }, )
    PH(0, 0, 1, 0, 1, { stage(0, 1, 1, kT1); }, )
    PH(0, 1, 1, 1, 0, if (m2) { stage(0, 0, 0, kT2); }, )
    PH(0, 1, 0, 0, 1, if (m2) { stage(1, 0, 1, kT2); },
       if (m2) { VMC6; } else { VMC2; })
    PH(1, 0, 0, 1, 1, if (m2) { stage(1, 0, 0, kT2); }, )
    PH(1, 0, 1, 0, 1, if (m2) { stage(0, 0, 1, kT2); },
       if (m2) { VMC8; } else { VMC0; })
    PH(1, 1, 1, 1, 0, if (m2) { stage(0, 1, 0, kT3); }, )
    PH(1, 1, 0, 0, 1, , if (m2) { VMC2; })
  }
#undef PH
  int frow = g4 << 2;
  #pragma unroll
  for (int rt = 0; rt < 8; rt++) {
    int qa = rt >> 2, i = rt & 3;
    int grow = m0 + (qa << 7) + (wrow << 6) + (i << 4) + frow;
    #pragma unroll
    for (int ct = 0; ct < 4; ct++) {
      int qb = ct >> 1, j = ct & 1;
      int gcol = n0 + (qb << 7) + (wcol << 5) + (j << 4) + lrow;
      float bb = bias ? bias[gcol] : 0.f;
      f32x4 av = acc[rt][ct];
      #pragma unroll
      for (int r = 0; r < 4; r++) {
        float vv = av[r] + bb;
        if (relu) vv = fmaxf(vv, 0.f);
        if (o32) o32[(size_t)(grow + r) * N + gcol] = vv;
        else obf[(size_t)(grow + r) * N + gcol] = f2bf(vv);
      }
    }
  }
}

// ---------------- m97-structure GEMM (layer GEMMs) ----------------
__global__ __launch_bounds__(256) void gemm_bt(
    const unsigned short* __restrict__ A,
    const unsigned short* __restrict__ Bt0, const unsigned short* __restrict__ Bt1,
    const unsigned short* __restrict__ Bt2,
    const float* __restrict__ bias, const float* resid,
    unsigned short* __restrict__ ob0, unsigned short* __restrict__ ob1,
    unsigned short* __restrict__ vtout, float* o32,
    int M, int N, int K, int relu) {
  __shared__ unsigned short As[128 * 64];
  __shared__ unsigned short Bs[128 * 64];
  int nbp = N >> 7;
  int which = blockIdx.x / nbp;
  int bx = blockIdx.x - which * nbp;
  const unsigned short* Bt = which == 0 ? Bt0 : (which == 1 ? Bt1 : Bt2);
  int m0 = blockIdx.y << 7, n0 = bx << 7;
  int tid = threadIdx.x, lane = tid & 63, wave = tid >> 6;
  int wr = (wave >> 1) << 6, wc = (wave & 1) << 6;
  int lrow = lane & 15, lk8 = (lane >> 4) << 3;
  int wbase = wave << 12;
  f32x4 acc[4][4] = {};
  const unsigned short* Ag = A + (size_t)m0 * K;
  const unsigned short* Bg = Bt + (size_t)n0 * K;
  for (int k0 = 0; k0 < K; k0 += 64) {
    #pragma unroll
    for (int i = 0; i < 4; i++) {
      int o = wbase + (i << 10) + (lane << 4);
      int r = o >> 7, c = (o & 127) >> 1;
      gload16(Ag + (size_t)r * K + k0 + c, (char*)As + wbase + (i << 10));
      gload16(Bg + (size_t)r * K + k0 + c, (char*)Bs + wbase + (i << 10));
    }
    __syncthreads();
    #pragma unroll
    for (int ks = 0; ks < 2; ks++) {
      bf16x8 af[4], bfv[4];
      #pragma unroll
      for (int i = 0; i < 4; i++)
        af[i] = *(const bf16x8*)(As + ((wr + (i << 4) + lrow) << 6) + (ks << 5) + lk8);
      #pragma unroll
      for (int i = 0; i < 4; i++)
        bfv[i] = *(const bf16x8*)(Bs + ((wc + (i << 4) + lrow) << 6) + (ks << 5) + lk8);
      #pragma unroll
      for (int mi = 0; mi < 4; mi++)
        #pragma unroll
        for (int ni = 0; ni < 4; ni++)
          acc[mi][ni] = __builtin_amdgcn_mfma_f32_16x16x32_bf16(af[mi], bfv[ni], acc[mi][ni], 0, 0, 0);
    }
    __syncthreads();
  }
  int fr = (lane >> 4) << 2;
  #pragma unroll
  for (int mi = 0; mi < 4; mi++) {
    #pragma unroll
    for (int ni = 0; ni < 4; ni++) {
      int row = m0 + wr + (mi << 4) + fr;
      int col = n0 + wc + (ni << 4) + lrow;
      f32x4 av = acc[mi][ni];
      if (bias) {
        float bb = bias[col];
        av[0] += bb; av[1] += bb; av[2] += bb; av[3] += bb;
      }
      if (relu) {
        av[0] = fmaxf(av[0], 0.f); av[1] = fmaxf(av[1], 0.f);
        av[2] = fmaxf(av[2], 0.f); av[3] = fmaxf(av[3], 0.f);
      }
      if (which == 2) {
        u32x2 pk;
        pk[0] = (unsigned int)f2bf(av[0]) | ((unsigned int)f2bf(av[1]) << 16);
        pk[1] = (unsigned int)f2bf(av[2]) | ((unsigned int)f2bf(av[3]) << 16);
        *(u32x2*)(vtout + (((size_t)(row >> 10) * 16 + (col >> 6)) * 64 + (col & 63)) * 1024
                  + (row & 1023)) = pk;
      } else if (o32) {
        #pragma unroll
        for (int r = 0; r < 4; r++) {
          size_t off = (size_t)(row + r) * N + col;
          float vvv = av[r];
          if (resid) vvv += resid[off];
          o32[off] = vvv;
        }
      } else {
        unsigned short* ob = which == 0 ? ob0 : ob1;
        #pragma unroll
        for (int r = 0; r < 4; r++)
          ob[(size_t)(row + r) * N + col] = f2bf(av[r]);
      }
    }
  }
}

// ---------------- split-K GEMM: partial f32, no epilogue ----------------
__global__ __launch_bounds__(256) void gemm_splitk(
    const unsigned short* __restrict__ A, const unsigned short* __restrict__ Bt,
    float* __restrict__ pbuf, int M, int N, int K, int KS) {
  __shared__ unsigned short As[128 * 64];
  __shared__ unsigned short Bs[128 * 64];
  int m0 = blockIdx.y << 7, n0 = blockIdx.x << 7;
  int kz = blockIdx.z * KS;
  int tid = threadIdx.x, lane = tid & 63, wave = tid >> 6;
  int wr = (wave >> 1) << 6, wc = (wave & 1) << 6;
  int lrow = lane & 15, lk8 = (lane >> 4) << 3;
  int wbase = wave << 12;
  f32x4 acc[4][4] = {};
  const unsigned short* Ag = A + (size_t)m0 * K;
  const unsigned short* Bg = Bt + (size_t)n0 * K;
  for (int k0 = kz; k0 < kz + KS; k0 += 64) {
    #pragma unroll
    for (int i = 0; i < 4; i++) {
      int o = wbase + (i << 10) + (lane << 4);
      int r = o >> 7, c = (o & 127) >> 1;
      gload16(Ag + (size_t)r * K + k0 + c, (char*)As + wbase + (i << 10));
      gload16(Bg + (size_t)r * K + k0 + c, (char*)Bs + wbase + (i << 10));
    }
    __syncthreads();
    #pragma unroll
    for (int ks = 0; ks < 2; ks++) {
      bf16x8 af[4], bfv[4];
      #pragma unroll
      for (int i = 0; i < 4; i++)
        af[i] = *(const bf16x8*)(As + ((wr + (i << 4) + lrow) << 6) + (ks << 5) + lk8);
      #pragma unroll
      for (int i = 0; i < 4; i++)
        bfv[i] = *(const bf16x8*)(Bs + ((wc + (i << 4) + lrow) << 6) + (ks << 5) + lk8);
      #pragma unroll
      for (int mi = 0; mi < 4; mi++)
        #pragma unroll
        for (int ni = 0; ni < 4; ni++)
          acc[mi][ni] = __builtin_amdgcn_mfma_f32_16x16x32_bf16(af[mi], bfv[ni], acc[mi][ni], 0, 0, 0);
    }
    __syncthreads();
  }
  int fr = (lane >> 4) << 2;
  float* pb = pbuf + (size_t)blockIdx.z * M * N;
  #pragma unroll
  for (int mi = 0; mi < 4; mi++)
    #pragma unroll
    for (int ni = 0; ni < 4; ni++) {
      int row = m0 + wr + (mi << 4) + fr;
      int col = n0 + wc + (ni << 4) + lrow;
      #pragma unroll
      for (int r = 0; r < 4; r++)
        pb[(size_t)(row + r) * N + col] = acc[mi][ni][r];
    }
}

// x[row][c] += bias[c] + sum_z pbuf[z][row][c]   (M=2048, N=1024)
__global__ __launch_bounds__(256) void reduce_k(float* __restrict__ x,
    const float* __restrict__ pbuf, const float* __restrict__ bias, int nz) {
  int row = blockIdx.x, c = threadIdx.x << 2;
  size_t off = ((size_t)row << 10) + c;
  f32x4 s = *(const f32x4*)(bias + c);
  for (int z = 0; z < nz; z++)
    s += *(const f32x4*)(pbuf + ((size_t)z << 21) + off);
  f32x4 xv = *(const f32x4*)(x + off);
  xv += s;
  *(f32x4*)(x + off) = xv;
}

// ---------------- windowed flash attention, KVBLK=64, 4 waves ----------------
// mask: row t attends s in [511-(t>>1), 511+((t+1)>>1)] (contiguous).
// Every row's window provably intersects the first 64-aligned tile, so the
// online max is finite after tile 0 (no exp(0) trap on all-invalid tiles).
__global__ __launch_bounds__(256) void attn64_k(
    const unsigned short* __restrict__ q, const unsigned short* __restrict__ k,
    const unsigned short* __restrict__ vt, unsigned short* __restrict__ att) {
  __shared__ unsigned short Ks[64 * 72];     // [s][hd]
  __shared__ unsigned short Vs[64 * 72];     // [hd][s]
  __shared__ unsigned short Ps[4][16 * 72];  // per-wave [row][s]
  int t0 = blockIdx.x << 6;
  int h = blockIdx.y, b = blockIdx.z;
  int tid = threadIdx.x, lane = tid & 63, w = tid >> 6;
  int lrow = lane & 15, lk8 = (lane >> 4) << 3, fr = (lane >> 4) << 2;
  int qrow = t0 + (w << 4) + lrow;
  size_t qoff = ((size_t)((b << 10) + qrow) << 10) + (h << 6);
  bf16x8 a0 = *(const bf16x8*)(q + qoff + lk8);
  bf16x8 a1 = *(const bf16x8*)(q + qoff + 32 + lk8);
  float m_[4] = {-1e30f, -1e30f, -1e30f, -1e30f};
  float l_[4] = {0.f, 0.f, 0.f, 0.f};
  f32x4 o_[4] = {};
  int s_lo = (511 - ((t0 + 63) >> 1)) & ~63;
  int s_hi = 511 + ((t0 + 64) >> 1);
  int s_end = (s_hi + 64) & ~63;             // exclusive, <=1024
  int krow = tid >> 2, kc = (tid & 3) << 4;  // 4 thr/row, 16 shorts each
  size_t vbase = ((size_t)((b << 4) + h) << 16) + ((size_t)krow << 10);
  unsigned short* Psw = &Ps[w][0];
  for (int s0 = s_lo; s0 < s_end; s0 += 64) {
    size_t koff = (((size_t)((b << 10) + s0 + krow)) << 10) + (h << 6) + kc;
    u32x4 kv0 = *(const u32x4*)(k + koff);
    u32x4 kv1 = *(const u32x4*)(k + koff + 8);
    u32x4 vv0 = *(const u32x4*)(vt + vbase + s0 + kc);
    u32x4 vv1 = *(const u32x4*)(vt + vbase + s0 + kc + 8);
    *(u32x4*)(Ks + krow * 72 + kc) = kv0;
    *(u32x4*)(Ks + krow * 72 + kc + 8) = kv1;
    *(u32x4*)(Vs + krow * 72 + kc) = vv0;
    *(u32x4*)(Vs + krow * 72 + kc + 8) = vv1;
    __syncthreads();
    f32x4 sc[4];
    #pragma unroll
    for (int sb = 0; sb < 4; sb++) {
      f32x4 z = {};
      bf16x8 kb0 = *(const bf16x8*)(Ks + ((sb << 4) + lrow) * 72 + lk8);
      bf16x8 kb1 = *(const bf16x8*)(Ks + ((sb << 4) + lrow) * 72 + 32 + lk8);
      z = __builtin_amdgcn_mfma_f32_16x16x32_bf16(a0, kb0, z, 0, 0, 0);
      z = __builtin_amdgcn_mfma_f32_16x16x32_bf16(a1, kb1, z, 0, 0, 0);
      sc[sb] = z;
    }
    #pragma unroll
    for (int r = 0; r < 4; r++) {
      int t = t0 + (w << 4) + fr + r;
      int lov = 511 - (t >> 1), hiv = 511 + ((t + 1) >> 1);
      float px[4];
      float tm = -1e30f;
      #pragma unroll
      for (int sb = 0; sb < 4; sb++) {
        int sX = s0 + (sb << 4) + lrow;
        bool vX = (sX >= lov) && (sX <= hiv);
        float x = vX ? sc[sb][r] * 0.125f : -1e30f;
        px[sb] = x;
        tm = fmaxf(tm, x);
      }
      #pragma unroll
      for (int off = 8; off; off >>= 1) tm = fmaxf(tm, __shfl_xor(tm, off));
      float nm = fmaxf(m_[r], tm);
      float sca = __expf(m_[r] - nm);
      m_[r] = nm;
      float ps = 0.f;
      #pragma unroll
      for (int sb = 0; sb < 4; sb++) {
        float pv = __expf(px[sb] - nm);   // invalid -> exp(-inf) = 0
        ps += pv;
        Psw[(fr + r) * 72 + (sb << 4) + lrow] = f2bf(pv);
      }
      #pragma unroll
      for (int off = 8; off; off >>= 1) ps += __shfl_xor(ps, off);
      l_[r] = l_[r] * sca + ps;
      #pragma unroll
      for (int nb = 0; nb < 4; nb++) o_[nb][r] *= sca;
    }
    bf16x8 pa0 = *(const bf16x8*)(Psw + lrow * 72 + lk8);
    bf16x8 pa1 = *(const bf16x8*)(Psw + lrow * 72 + 32 + lk8);
    #pragma unroll
    for (int nb = 0; nb < 4; nb++) {
      bf16x8 vb0 = *(const bf16x8*)(Vs + ((nb << 4) + lrow) * 72 + lk8);
      bf16x8 vb1 = *(const bf16x8*)(Vs + ((nb << 4) + lrow) * 72 + 32 + lk8);
      o_[nb] = __builtin_amdgcn_mfma_f32_16x16x32_bf16(pa0, vb0, o_[nb], 0, 0, 0);
      o_[nb] = __builtin_amdgcn_mfma_f32_16x16x32_bf16(pa1, vb1, o_[nb], 0, 0, 0);
    }
    __syncthreads();
  }
  #pragma unroll
  for (int nb = 0; nb < 4; nb++)
    #pragma unroll
    for (int r = 0; r < 4; r++) {
      float ov = o_[nb][r] / l_[r];
      att[((size_t)((b << 10) + t0 + (w << 4) + fr + r) << 10) + (h << 6) + (nb << 4) + lrow]
          = f2bf(ov);
    }
}

extern "C" void kernel_launch(void* const* d_in, const int* in_sizes, int n_in,
                              void* d_out, int out_size, void* d_ws, size_t ws_size,
                              hipStream_t stream) {
  (void)in_sizes; (void)n_in; (void)out_size;
  const int*   idx  = (const int*)d_in[0];
  const float* tok  = (const float*)d_in[1];
  const float* pos  = (const float*)d_in[2];
  const float* ln1g = (const float*)d_in[3];
  const float* ln1b = (const float*)d_in[4];
  const float* wq   = (const float*)d_in[5];
  const float* wk   = (const float*)d_in[6];
  const float* wv   = (const float*)d_in[7];
  const float* wpj  = (const float*)d_in[8];
  const float* bpj  = (const float*)d_in[9];
  const float* ln2g = (const float*)d_in[10];
  const float* ln2b = (const float*)d_in[11];
  const float* w1   = (const float*)d_in[12];
  const float* b1   = (const float*)d_in[13];
  const float* w2   = (const float*)d_in[14];
  const float* b2   = (const float*)d_in[15];
  const float* lnfg = (const float*)d_in[16];
  const float* lnfb = (const float*)d_in[17];
  const float* wlm  = (const float*)d_in[18];
  const float* blm  = (const float*)d_in[19];
  float* out = (float*)d_out;

  char* ws = (char*)d_ws;
  const size_t MB = 1u << 20;
  float*          x    = (float*)ws;
  unsigned short* hb   = (unsigned short*)(ws + 8 * MB);
  unsigned short* qb   = (unsigned short*)(ws + 12 * MB);
  unsigned short* kb   = (unsigned short*)(ws + 16 * MB);
  unsigned short* vbuf = (unsigned short*)(ws + 20 * MB);
  unsigned short* ab   = (unsigned short*)(ws + 24 * MB);
  unsigned short* m1   = (unsigned short*)(ws + 28 * MB);
  const int M = 2048, D = 1024;

  int nz; float* pb;
  if (ws_size >= 408 * MB) { nz = 4; pb = (float*)(ws + 376 * MB); }
  else                     { nz = 2; pb = (float*)(ws + 8 * MB); }

  embed_k<<<dim3(2048), dim3(256), 0, stream>>>(idx, tok, pos, x);

  unsigned short* wqT  = (unsigned short*)(ws + 44 * MB);
  unsigned short* wkT  = (unsigned short*)(ws + 60 * MB);
  unsigned short* wvT  = (unsigned short*)(ws + 76 * MB);
  unsigned short* wpT  = (unsigned short*)(ws + 92 * MB);
  unsigned short* w1T  = (unsigned short*)(ws + 108 * MB);
  unsigned short* w2T  = (unsigned short*)(ws + 172 * MB);
  unsigned short* wlmT = (unsigned short*)(ws + 236 * MB);
  transp_k<<<dim3(16, 16, 8), 256, 0, stream>>>(wq,   wqT,  1024, 1024);
  transp_k<<<dim3(16, 16, 8), 256, 0, stream>>>(wk,   wkT,  1024, 1024);
  transp_k<<<dim3(16, 16, 8), 256, 0, stream>>>(wv,   wvT,  1024, 1024);
  transp_k<<<dim3(16, 16, 8), 256, 0, stream>>>(wpj,  wpT,  1024, 1024);
  transp_k<<<dim3(64, 16, 8), 256, 0, stream>>>(w1,   w1T,  1024, 4096);
  transp_k<<<dim3(16, 64, 8), 256, 0, stream>>>(w2,   w2T,  4096, 1024);
  transp_k<<<dim3(1000, 16, 1), 256, 0, stream>>>(wlm, wlmT, 1024, 64000);
  for (int l = 0; l < 8; l++) {
    size_t wo = (size_t)l << 20;
    ln_k<<<2048, 256, 0, stream>>>(x, ln1g + l*D, ln1b + l*D, hb);
    gemm_bt<<<dim3(24, 16), 256, 0, stream>>>(hb, wqT + wo, wkT + wo, wvT + wo,
        nullptr, nullptr, qb, kb, vbuf, nullptr, M, D, D, 0);
    attn64_k<<<dim3(16, 16, 2), 256, 0, stream>>>(qb, kb, vbuf, ab);
    gemm_bt<<<dim3(8, 16), 256, 0, stream>>>(ab, wpT + wo, nullptr, nullptr,
        bpj + l*D, x, nullptr, nullptr, nullptr, x, M, D, D, 0);
    ln_k<<<2048, 256, 0, stream>>>(x, ln2g + l*D, ln2b + l*D, hb);
    gemm_bt<<<dim3(32, 16), 256, 0, stream>>>(hb, w1T + ((size_t)l << 22), nullptr, nullptr,
        b1 + (size_t)l*4*D, nullptr, m1, nullptr, nullptr, nullptr, M, 4*D, D, 1);
    gemm_splitk<<<dim3(8, 16, nz), 256, 0, stream>>>(m1, w2T + ((size_t)l << 22),
        pb, M, D, 4*D, 4*D / nz);
    reduce_k<<<2048, 256, 0, stream>>>(x, pb, b2 + l*D, nz);
  }
  ln_k<<<2048, 256, 0, stream>>>(x, lnfg, lnfb, hb);
  gemm256_k<<<dim3(2000), 512, 0, stream>>>(hb, wlmT,
      blm, out, nullptr, M, 64000, D, 0);
}